// Round 9
// baseline (551.871 us; speedup 1.0000x reference)
//
#include <hip/hip_runtime.h>
#include <cstdint>

#ifndef JAX_PARTITIONABLE
#define JAX_PARTITIONABLE 1   // modern JAX (>=0.5) default threefry_partitionable
#endif

#define NCELLS (128*128*128)          // 2,097,152
#define SCAN_BLOCKS 1024              // NCELLS / 2048
#define NQBINS (32*32*32)             // coarse query bins (4x4x4 cells each)

// ---------------- Threefry-2x32, key = (0, 42)  (jax.random.key(42)) ----------------
__device__ __forceinline__ uint32_t rotl32(uint32_t v, int s){ return (v << s) | (v >> (32 - s)); }

__device__ __forceinline__ void tf2x32(uint32_t& x0, uint32_t& x1){
  const uint32_t k0 = 0u, k1 = 42u;
  const uint32_t k2 = 0x1BD11BDAu ^ k0 ^ k1;
  x0 += k0; x1 += k1;
#define TFR(r) { x0 += x1; x1 = rotl32(x1,(r)); x1 ^= x0; }
  TFR(13) TFR(15) TFR(26) TFR(6)
  x0 += k1; x1 += k2 + 1u;
  TFR(17) TFR(29) TFR(16) TFR(24)
  x0 += k2; x1 += k0 + 2u;
  TFR(13) TFR(15) TFR(26) TFR(6)
  x0 += k0; x1 += k1 + 3u;
  TFR(17) TFR(29) TFR(16) TFR(24)
  x0 += k1; x1 += k2 + 4u;
  TFR(13) TFR(15) TFR(26) TFR(6)
  x0 += k2; x1 += k0 + 5u;
#undef TFR
}

// XLA f32 ErfInv (Giles) — exact coefficient match with jax/XLA
__device__ __forceinline__ float erfinv_xla(float x){
  float w = -log1pf(-x*x);
  float p;
  if (w < 5.0f){
    w -= 2.5f;
    p =  2.81022636e-08f;
    p = fmaf(p,w, 3.43273939e-07f);
    p = fmaf(p,w,-3.5233877e-06f);
    p = fmaf(p,w,-4.39150654e-06f);
    p = fmaf(p,w, 0.00021858087f);
    p = fmaf(p,w,-0.00125372503f);
    p = fmaf(p,w,-0.00417768164f);
    p = fmaf(p,w, 0.246640727f);
    p = fmaf(p,w, 1.50140941f);
  } else {
    w = sqrtf(w) - 3.0f;
    p = -0.000200214257f;
    p = fmaf(p,w, 0.000100950558f);
    p = fmaf(p,w, 0.00134934322f);
    p = fmaf(p,w,-0.00367342844f);
    p = fmaf(p,w, 0.00573950773f);
    p = fmaf(p,w,-0.0076224613f);
    p = fmaf(p,w, 0.00943887047f);
    p = fmaf(p,w, 1.00167406f);
    p = fmaf(p,w, 2.83297682f);
  }
  return p*x;
}

// noise[i] = 0.8 * sqrt(2)*erfinv(uniform(-1,1)) with jax bit semantics
__device__ __forceinline__ float noise_at(uint32_t idx, uint32_t half){
#if JAX_PARTITIONABLE
  (void)half;
  uint32_t x0 = 0u, x1 = idx;     // counter = (hi=0, lo=i)
  tf2x32(x0, x1);
  uint32_t bits = x0 ^ x1;        // partitionable 32-bit path: xor-fold of both words
#else
  uint32_t j  = (idx < half) ? idx : (idx - half);
  uint32_t x0 = j, x1 = j + half;
  tf2x32(x0, x1);
  uint32_t bits = (idx < half) ? x0 : x1;
#endif
  float f = __uint_as_float((bits >> 9) | 0x3f800000u) - 1.0f;      // [0,1)
  float u = fmaxf(-0.99999994f, fmaf(f, 2.0f, -0.99999994f));       // (-1,1)
  return (1.41421356f * erfinv_xla(u)) * 0.8f;
}

// jax.nn.gelu approximate=True
__device__ __forceinline__ float tanh_fast(float x){
  float e = __expf(2.0f * x);
  return 1.0f - 2.0f * __builtin_amdgcn_rcpf(e + 1.0f);
}
__device__ __forceinline__ float gelu_f(float x){
  float inner = 0.7978845608028654f * (x + 0.044715f*(x*x*x));
  return 0.5f * x * (1.0f + tanh_fast(inner));
}

// common per-particle geometry
__device__ __forceinline__ void particle_cell(const float* xsr, int i,
                                              float& sx, float& sy, float& sz,
                                              int& bx, int& by, int& bz,
                                              float& dx, float& dy, float& dz){
  sx = fminf(fmaxf(xsr[3*i+0], 0.0f), 1.0f);
  sy = fminf(fmaxf(xsr[3*i+1], 0.0f), 1.0f);
  sz = fminf(fmaxf(xsr[3*i+2], 0.0f), 1.0f);
  float cx = fminf(fmaxf(sx*127.0f, 0.0f), 126.999f);
  float cy = fminf(fmaxf(sy*127.0f, 0.0f), 126.999f);
  float cz = fminf(fmaxf(sz*127.0f, 0.0f), 126.999f);
  float bxf = floorf(cx), byf = floorf(cy), bzf = floorf(cz);
  bx = (int)bxf; by = (int)byf; bz = (int)bzf;
  dx = cx - bxf; dy = cy - byf; dz = cz - bzf;
}

// ---------------- particle binning pipeline ----------------
__global__ void __launch_bounds__(256) hist_kernel(const float* __restrict__ xsr,
                                                   int* __restrict__ cnt, int N){
  int i = blockIdx.x*256 + threadIdx.x;
  if (i >= N) return;
  float sx,sy,sz,dx,dy,dz; int bx,by,bz;
  particle_cell(xsr,i,sx,sy,sz,bx,by,bz,dx,dy,dz);
  int bin = (((bx<<7)+by)<<7)+bz;
  atomicAdd(&cnt[bin], 1);
}

// exclusive scan stage 1: 1024 blocks x 256 thr x 8 elems
__global__ void __launch_bounds__(256) scan1_kernel(const int* __restrict__ cnt,
                                                    int* __restrict__ offs,
                                                    int* __restrict__ bsum){
  __shared__ int lds[256];
  int t = threadIdx.x;
  int base = blockIdx.x*2048 + t*8;
  const int4* c4 = reinterpret_cast<const int4*>(cnt + base);
  int4 a0 = c4[0], a1 = c4[1];
  int s = a0.x+a0.y+a0.z+a0.w + a1.x+a1.y+a1.z+a1.w;
  lds[t] = s; __syncthreads();
  for (int off = 1; off < 256; off <<= 1){
    int v = (t >= off) ? lds[t-off] : 0;
    __syncthreads();
    lds[t] += v;
    __syncthreads();
  }
  int run = lds[t] - s;               // exclusive prefix of this thread's chunk
  if (t == 255) bsum[blockIdx.x] = lds[255];
  int* o = offs + base;
  o[0]=run; run+=a0.x; o[1]=run; run+=a0.y; o[2]=run; run+=a0.z; o[3]=run; run+=a0.w;
  o[4]=run; run+=a1.x; o[5]=run; run+=a1.y; o[6]=run; run+=a1.z; o[7]=run;
}

// stage 2: single block scans the 1024 block sums (exclusive), writes grand total at [1024]
__global__ void __launch_bounds__(1024) scan2_kernel(int* __restrict__ bsum){
  __shared__ int lds[1024];
  int t = threadIdx.x;
  int v = bsum[t];
  lds[t] = v; __syncthreads();
  for (int off = 1; off < 1024; off <<= 1){
    int u = (t >= off) ? lds[t-off] : 0;
    __syncthreads();
    lds[t] += u;
    __syncthreads();
  }
  bsum[t] = lds[t] - v;
  if (t == 1023) bsum[1024] = lds[1023];
}

// stage 3: add block offsets, init cursor, write sentinel
__global__ void __launch_bounds__(256) scan3_kernel(int* __restrict__ offs,
                                                    const int* __restrict__ bsum,
                                                    int* __restrict__ cursor){
  int i = blockIdx.x*256 + threadIdx.x;     // exactly NCELLS threads
  int o = offs[i] + bsum[i >> 11];
  offs[i] = o; cursor[i] = o;
  if (i == 0) offs[NCELLS] = bsum[SCAN_BLOCKS];
}

__global__ void __launch_bounds__(256) scatter_kernel(
    const float* __restrict__ xsr, const float* __restrict__ xsc,
    const float* __restrict__ Wf,  const float* __restrict__ bf,
    int* __restrict__ cursor,
    float4* __restrict__ pf, float4* __restrict__ pu, float* __restrict__ pz, int N){
  int i = blockIdx.x*256 + threadIdx.x;
  if (i >= N) return;
  float sx,sy,sz,dx,dy,dz; int bx,by,bz;
  particle_cell(xsr,i,sx,sy,sz,bx,by,bz,dx,dy,dz);
  float ux = xsc[3*i+0] - sx;
  float uy = xsc[3*i+1] - sy;
  float uz = xsc[3*i+2] - sz;
  float f0 = gelu_f(ux*Wf[0] + uy*Wf[3] + uz*Wf[6] + bf[0]);
  float f1 = gelu_f(ux*Wf[1] + uy*Wf[4] + uz*Wf[7] + bf[1]);
  float f2 = gelu_f(ux*Wf[2] + uy*Wf[5] + uz*Wf[8] + bf[2]);
  int bin = (((bx<<7)+by)<<7)+bz;
  int pos = atomicAdd(&cursor[bin], 1);
  pf[pos] = make_float4(f0, f1, f2, dx);
  pu[pos] = make_float4(ux, uy, uz, dy);
  pz[pos] = dz;
}

// z-pair per-cell gather: thread owns cells (x,y,z0) and (x,y,z0+1), z0 even.
__global__ void __launch_bounds__(256) p2g_gather_pair_kernel(
    const int* __restrict__ offs,
    const float4* __restrict__ pf, const float4* __restrict__ pu,
    const float* __restrict__ pz, float* __restrict__ grid){
  int tid = blockIdx.x*256 + threadIdx.x;   // exactly NCELLS/2 threads
  int zg = tid & 63, y = (tid >> 6) & 127, x = tid >> 13;
  int z0 = zg << 1;
  float a0[2]={0,0},a1[2]={0,0},a2[2]={0,0},a3[2]={0,0},a4[2]={0,0},a5[2]={0,0},a6[2]={0,0};
#pragma unroll
  for (int ox = 0; ox < 2; ++ox){
    int bx = x - ox; if (bx < 0) continue;
#pragma unroll
    for (int oy = 0; oy < 2; ++oy){
      int by = y - oy; if (by < 0) continue;
      int b0 = ((((bx<<7)+by)<<7)) + z0;
      int em = offs[b0];
      int sm = (z0 > 0) ? offs[b0-1] : em;
      int e0 = offs[b0+1];
      int e1 = offs[b0+2];
      for (int p = sm; p < em; ++p){
        float4 A = pf[p]; float4 B = pu[p]; float dz = pz[p];
        float wx = ox ? A.w : 1.0f - A.w;
        float wy = oy ? B.w : 1.0f - B.w;
        float w = wx*wy*dz;
        a0[0]=fmaf(A.x,w,a0[0]); a1[0]=fmaf(A.y,w,a1[0]); a2[0]=fmaf(A.z,w,a2[0]);
        a3[0]+=w; a4[0]=fmaf(B.x,w,a4[0]); a5[0]=fmaf(B.y,w,a5[0]); a6[0]=fmaf(B.z,w,a6[0]);
      }
      for (int p = em; p < e0; ++p){
        float4 A = pf[p]; float4 B = pu[p]; float dz = pz[p];
        float wx = ox ? A.w : 1.0f - A.w;
        float wy = oy ? B.w : 1.0f - B.w;
        float wxy = wx*wy;
        float w0 = wxy*(1.0f-dz), w1 = wxy*dz;
        a0[0]=fmaf(A.x,w0,a0[0]); a1[0]=fmaf(A.y,w0,a1[0]); a2[0]=fmaf(A.z,w0,a2[0]);
        a3[0]+=w0; a4[0]=fmaf(B.x,w0,a4[0]); a5[0]=fmaf(B.y,w0,a5[0]); a6[0]=fmaf(B.z,w0,a6[0]);
        a0[1]=fmaf(A.x,w1,a0[1]); a1[1]=fmaf(A.y,w1,a1[1]); a2[1]=fmaf(A.z,w1,a2[1]);
        a3[1]+=w1; a4[1]=fmaf(B.x,w1,a4[1]); a5[1]=fmaf(B.y,w1,a5[1]); a6[1]=fmaf(B.z,w1,a6[1]);
      }
      for (int p = e0; p < e1; ++p){
        float4 A = pf[p]; float4 B = pu[p]; float dz = pz[p];
        float wx = ox ? A.w : 1.0f - A.w;
        float wy = oy ? B.w : 1.0f - B.w;
        float w = wx*wy*(1.0f-dz);
        a0[1]=fmaf(A.x,w,a0[1]); a1[1]=fmaf(A.y,w,a1[1]); a2[1]=fmaf(A.z,w,a2[1]);
        a3[1]+=w; a4[1]=fmaf(B.x,w,a4[1]); a5[1]=fmaf(B.y,w,a5[1]); a6[1]=fmaf(B.z,w,a6[1]);
      }
    }
  }
  int cell0 = ((((x<<7)+y)<<7)) + z0;
  float4* g = reinterpret_cast<float4*>(grid + ((size_t)cell0 << 3));
  g[0] = make_float4(a0[0],a1[0],a2[0],a3[0]);
  g[1] = make_float4(a4[0],a5[0],a6[0],0.0f);
  g[2] = make_float4(a0[1],a1[1],a2[1],a3[1]);
  g[3] = make_float4(a4[1],a5[1],a6[1],0.0f);
}

// ---------------- coarse query binning (32^3 bins of 4^3 cells) ----------------
__device__ __forceinline__ int qbin_of(float qx01, float qy01, float qz01){
  int bx = min((int)(qx01*127.0f), 127) >> 2;
  int by = min((int)(qy01*127.0f), 127) >> 2;
  int bz = min((int)(qz01*127.0f), 127) >> 2;
  return (((bx<<5)+by)<<5)+bz;
}

__global__ void __launch_bounds__(256) qhist_kernel(const float* __restrict__ xq,
                                                    int* __restrict__ cnt, int M){
  int i = blockIdx.x*256 + threadIdx.x;
  if (i >= M) return;
  float qx01 = fminf(fmaxf(xq[3*i+0], 0.0f), 1.0f);
  float qy01 = fminf(fmaxf(xq[3*i+1], 0.0f), 1.0f);
  float qz01 = fminf(fmaxf(xq[3*i+2], 0.0f), 1.0f);
  atomicAdd(&cnt[qbin_of(qx01,qy01,qz01)], 1);
}

// single-block exclusive scan over NQBINS counts -> cursor init
__global__ void __launch_bounds__(1024) qscan_kernel(const int* __restrict__ cnt,
                                                     int* __restrict__ cursor){
  __shared__ int lds[1024];
  int t = threadIdx.x;
  int base = t*32;
  int loc[32];
  int s = 0;
#pragma unroll
  for (int j = 0; j < 32; ++j){ loc[j] = cnt[base+j]; s += loc[j]; }
  lds[t] = s; __syncthreads();
  for (int off = 1; off < 1024; off <<= 1){
    int u = (t >= off) ? lds[t-off] : 0;
    __syncthreads();
    lds[t] += u;
    __syncthreads();
  }
  int run = lds[t] - s;
#pragma unroll
  for (int j = 0; j < 32; ++j){ cursor[base+j] = run; run += loc[j]; }
}

// query scatter: stash clipped coords + original index in coarse-sorted order
__global__ void __launch_bounds__(256) qscatter_kernel(
    const float* __restrict__ xq, int* __restrict__ cursor,
    float* __restrict__ qs, int* __restrict__ qidx, int M){
  int i = blockIdx.x*256 + threadIdx.x;
  if (i >= M) return;
  float qx01 = fminf(fmaxf(xq[3*i+0], 0.0f), 1.0f);
  float qy01 = fminf(fmaxf(xq[3*i+1], 0.0f), 1.0f);
  float qz01 = fminf(fmaxf(xq[3*i+2], 0.0f), 1.0f);
  int pos = atomicAdd(&cursor[qbin_of(qx01,qy01,qz01)], 1);
  qs[3*pos+0] = qx01; qs[3*pos+1] = qy01; qs[3*pos+2] = qz01;
  qidx[pos] = i;
}

// ---------------- PASS A: 8-path MC trilerp gather -> dcc buffer ----------------
// Noise hoisted: all 24 threefry chains run first (pure VALU), then the sample
// loop is pure address+load+fma -> loads pipeline across iterations.
__global__ void __launch_bounds__(256) gather_pass_kernel(
    const float* __restrict__ qs,  const int* __restrict__ qidx,
    const float* __restrict__ grid, float* __restrict__ dcc, int M, int nblk)
{
  int b = blockIdx.x;
  int nb8 = (nblk >> 3) << 3;
  int c = (b < nb8) ? ((b & 7)*(nblk >> 3) + (b >> 3)) : b;   // XCD-contiguous chunks
  int t = c*256 + threadIdx.x;
  if (t >= M) return;
  int m = qidx[t];

  float qx = qs[3*t+0]*127.0f, qy = qs[3*t+1]*127.0f, qz = qs[3*t+2]*127.0f;

  const uint32_t KSTRIDE = 3u*(uint32_t)M;
  const uint32_t HALF    = 4u*KSTRIDE;
  uint32_t m3 = 3u*(uint32_t)m;

  float nz[24];
#pragma unroll
  for (int k = 0; k < 8; ++k){
    uint32_t base = (uint32_t)k*KSTRIDE + m3;
    nz[3*k+0] = noise_at(base+0u, HALF);
    nz[3*k+1] = noise_at(base+1u, HALF);
    nz[3*k+2] = noise_at(base+2u, HALF);
  }

  float r0=0.f,r1=0.f,r2=0.f,r3=0.f,r4=0.f,r5=0.f,r6=0.f;
#pragma unroll
  for (int k = 0; k < 8; ++k) {
    float px = qx + nz[3*k+0];
    float py = qy + nz[3*k+1];
    float pz = qz + nz[3*k+2];
    float fxf = floorf(px), fyf = floorf(py), fzf = floorf(pz);
    float fx = px - fxf, fy = py - fyf, fz = pz - fzf;
    int lx = (int)fxf, ly = (int)fyf, lz = (int)fzf;
    int x0i = min(max(lx,0),127),   x1i = min(max(lx+1,0),127);
    int y0i = min(max(ly,0),127),   y1i = min(max(ly+1,0),127);
    int z0i = min(max(lz,0),127),   z1i = min(max(lz+1,0),127);
    float ex = 1.0f-fx, ey = 1.0f-fy, ez = 1.0f-fz;

    auto corner = [&](int xi,int yi,int zi,float w){
      const float4* p = reinterpret_cast<const float4*>(grid + ((size_t)((((xi<<7)+yi)<<7)+zi) << 3));
      float4 g0 = p[0]; float4 g1 = p[1];
      r0 = fmaf(g0.x, w, r0); r1 = fmaf(g0.y, w, r1); r2 = fmaf(g0.z, w, r2);
      r3 = fmaf(g0.w, w, r3); r4 = fmaf(g1.x, w, r4); r5 = fmaf(g1.y, w, r5);
      r6 = fmaf(g1.z, w, r6);
    };
    corner(x0i,y0i,z0i, ex*ey*ez);
    corner(x0i,y0i,z1i, ex*ey*fz);
    corner(x0i,y1i,z0i, ex*fy*ez);
    corner(x0i,y1i,z1i, ex*fy*fz);
    corner(x1i,y0i,z0i, fx*ey*ez);
    corner(x1i,y0i,z1i, fx*ey*fz);
    corner(x1i,y1i,z0i, fx*fy*ez);
    corner(x1i,y1i,z1i, fx*fy*fz);
  }

  float dmean = r3*0.125f;
  float denom = fmaxf(dmean, 1e-5f);
  float maskf = (dmean > 1e-5f) ? 1.0f : 0.0f;
  float s = 0.125f/denom*maskf;
  float4* d4 = reinterpret_cast<float4*>(dcc + ((size_t)t<<3));
  d4[0] = make_float4(r0*s, r1*s, r2*s, r4*s);   // fn0,fn1,fn2,un0
  d4[1] = make_float4(r5*s, r6*s, 0.0f, 0.0f);   // un1,un2
}

// ---------------- PASS B: posenc + MLP (register-resident, fully unrolled) ----------------
// amdgpu_waves_per_eu(2,2): pin the allocator to a 256-VGPR budget so h[64]/g[32]
// stay in registers instead of being spilled to reach 8-waves/EU occupancy.
__global__ __attribute__((amdgpu_waves_per_eu(2, 2))) void __launch_bounds__(256) mlp_pass_kernel(
    const float* __restrict__ qs,  const int* __restrict__ qidx,
    const float* __restrict__ dcc,
    const float* __restrict__ W1,  const float* __restrict__ b1,
    const float* __restrict__ W2,  const float* __restrict__ b2,
    const float* __restrict__ W3,  const float* __restrict__ b3,
    float* __restrict__ out, int M)
{
  int t = blockIdx.x*256 + threadIdx.x;
  if (t >= M) return;
  float qx01 = qs[3*t+0], qy01 = qs[3*t+1], qz01 = qs[3*t+2];
  const float4* d4 = reinterpret_cast<const float4*>(dcc + ((size_t)t<<3));
  float4 dA = d4[0]; float4 dB = d4[1];
  float un0 = dA.w, un1 = dB.x, un2 = dB.y;

  float dec[24];
  dec[0]=dA.x; dec[1]=dA.y; dec[2]=dA.z; dec[3]=un0; dec[4]=un1; dec[5]=un2;
  dec[6]  = __builtin_amdgcn_sinf(0.5f*qx01);   // v_sin input is revolutions
  dec[7]  = __builtin_amdgcn_sinf(0.5f*qy01);
  dec[8]  = __builtin_amdgcn_sinf(0.5f*qz01);
  dec[9]  = __builtin_amdgcn_cosf(0.5f*qx01);
  dec[10] = __builtin_amdgcn_cosf(0.5f*qy01);
  dec[11] = __builtin_amdgcn_cosf(0.5f*qz01);
  dec[12] = __builtin_amdgcn_sinf(qx01);
  dec[13] = __builtin_amdgcn_sinf(qy01);
  dec[14] = __builtin_amdgcn_sinf(qz01);
  dec[15] = __builtin_amdgcn_cosf(qx01);
  dec[16] = __builtin_amdgcn_cosf(qy01);
  dec[17] = __builtin_amdgcn_cosf(qz01);
  dec[18] = __builtin_amdgcn_sinf(2.0f*qx01);
  dec[19] = __builtin_amdgcn_sinf(2.0f*qy01);
  dec[20] = __builtin_amdgcn_sinf(2.0f*qz01);
  dec[21] = __builtin_amdgcn_cosf(2.0f*qx01);
  dec[22] = __builtin_amdgcn_cosf(2.0f*qy01);
  dec[23] = __builtin_amdgcn_cosf(2.0f*qz01);

  float h[64];
#pragma unroll
  for (int j = 0; j < 64; ++j) h[j] = b1[j];
#pragma unroll
  for (int k2 = 0; k2 < 24; ++k2) {
    float dk = dec[k2];
    const float* __restrict__ wr = W1 + (k2<<6);
#pragma unroll
    for (int j = 0; j < 64; ++j) h[j] = fmaf(dk, wr[j], h[j]);
  }
#pragma unroll
  for (int j = 0; j < 64; ++j) h[j] = gelu_f(h[j]);

  float o0 = b3[0], o1 = b3[1], o2 = b3[2];
#pragma unroll
  for (int hlf = 0; hlf < 2; ++hlf) {
    float g[32];
#pragma unroll
    for (int j = 0; j < 32; ++j) g[j] = b2[(hlf<<5)+j];
#pragma unroll
    for (int k2 = 0; k2 < 64; ++k2) {
      float hk = h[k2];
      const float* __restrict__ wr = W2 + (k2<<6) + (hlf<<5);
#pragma unroll
      for (int j = 0; j < 32; ++j) g[j] = fmaf(hk, wr[j], g[j]);
    }
#pragma unroll
    for (int j = 0; j < 32; ++j) {
      float gg = gelu_f(g[j]);
      int col = (hlf<<5)+j;
      o0 = fmaf(gg, W3[3*col+0], o0);
      o1 = fmaf(gg, W3[3*col+1], o1);
      o2 = fmaf(gg, W3[3*col+2], o2);
    }
  }

  int m = qidx[t];
  out[3*m+0] = fminf(fmaxf(un0 + o0, 0.001f), 0.999f);
  out[3*m+1] = fminf(fmaxf(un1 + o1, 0.001f), 0.999f);
  out[3*m+2] = fminf(fmaxf(un2 + o2, 0.001f), 0.999f);
}

// ---------------- fallbacks (ws too small; not used in practice) ----------------
__global__ void __launch_bounds__(256) p2g_atomic_kernel(
    const float* __restrict__ xsr, const float* __restrict__ xsc,
    const float* __restrict__ Wf,  const float* __restrict__ bf,
    float* __restrict__ grid, int N)
{
  int i = blockIdx.x*256 + threadIdx.x;
  if (i >= N) return;
  float sx,sy,sz,dx,dy,dz; int bx,by,bz;
  particle_cell(xsr,i,sx,sy,sz,bx,by,bz,dx,dy,dz);
  float ux = xsc[3*i+0] - sx;
  float uy = xsc[3*i+1] - sy;
  float uz = xsc[3*i+2] - sz;
  float f0 = gelu_f(ux*Wf[0] + uy*Wf[3] + uz*Wf[6] + bf[0]);
  float f1 = gelu_f(ux*Wf[1] + uy*Wf[4] + uz*Wf[7] + bf[1]);
  float f2 = gelu_f(ux*Wf[2] + uy*Wf[5] + uz*Wf[8] + bf[2]);
  float ex = 1.0f - dx, ey = 1.0f - dy, ez = 1.0f - dz;
  auto splat = [&](int xi, int yi, int zi, float w){
    float* p = grid + ((size_t)((((xi<<7)+yi)<<7)+zi) << 3);
    unsafeAtomicAdd(p+0, f0*w);
    unsafeAtomicAdd(p+1, f1*w);
    unsafeAtomicAdd(p+2, f2*w);
    unsafeAtomicAdd(p+3, w);
    unsafeAtomicAdd(p+4, ux*w);
    unsafeAtomicAdd(p+5, uy*w);
    unsafeAtomicAdd(p+6, uz*w);
  };
  splat(bx,  by,  bz,   ex*ey*ez);
  splat(bx,  by,  bz+1, ex*ey*dz);
  splat(bx,  by+1,bz,   ex*dy*ez);
  splat(bx,  by+1,bz+1, ex*dy*dz);
  splat(bx+1,by,  bz,   dx*ey*ez);
  splat(bx+1,by,  bz+1, dx*ey*dz);
  splat(bx+1,by+1,bz,   dx*dy*ez);
  splat(bx+1,by+1,bz+1, dx*dy*dz);
}

// identity "sort" init for fallback (qs=clipped xq, qidx=i)
__global__ void __launch_bounds__(256) qident_kernel(
    const float* __restrict__ xq, float* __restrict__ qs, int* __restrict__ qidx, int M){
  int i = blockIdx.x*256 + threadIdx.x;
  if (i >= M) return;
  qs[3*i+0] = fminf(fmaxf(xq[3*i+0], 0.0f), 1.0f);
  qs[3*i+1] = fminf(fmaxf(xq[3*i+1], 0.0f), 1.0f);
  qs[3*i+2] = fminf(fmaxf(xq[3*i+2], 0.0f), 1.0f);
  qidx[i] = i;
}

extern "C" void kernel_launch(void* const* d_in, const int* in_sizes, int n_in,
                              void* d_out, int out_size, void* d_ws, size_t ws_size,
                              hipStream_t stream)
{
  const float* xq  = (const float*)d_in[0];
  const float* xsr = (const float*)d_in[1];
  const float* xsc = (const float*)d_in[2];
  const float* Wf  = (const float*)d_in[3];
  const float* bf  = (const float*)d_in[4];
  const float* W1  = (const float*)d_in[5];
  const float* b1  = (const float*)d_in[6];
  const float* W2  = (const float*)d_in[7];
  const float* b2  = (const float*)d_in[8];
  const float* W3  = (const float*)d_in[9];
  const float* b3  = (const float*)d_in[10];
  float* out  = (float*)d_out;
  int M = in_sizes[0]/3;
  int N = in_sizes[1]/3;

  // workspace layout (256B-aligned chunks)
  char* W = (char*)d_ws;
  size_t off = 0;
  auto alloc = [&](size_t bytes){ size_t o = off; off = (off + bytes + 255) & ~(size_t)255; return o; };
  size_t o_grid   = alloc((size_t)NCELLS * 8 * sizeof(float));   // 64 MiB
  size_t o_cnt    = alloc((size_t)NCELLS * sizeof(int));         // 8 MiB
  size_t o_offs   = alloc(((size_t)NCELLS + 1) * sizeof(int));   // 8 MiB
  size_t o_cursor = alloc((size_t)NCELLS * sizeof(int));         // 8 MiB
  size_t o_bsum   = alloc((size_t)(SCAN_BLOCKS + 1) * sizeof(int));
  size_t o_pf     = alloc((size_t)N * sizeof(float4));           // 8 MB
  size_t o_pu     = alloc((size_t)N * sizeof(float4));           // 8 MB
  size_t o_pz     = alloc((size_t)N * sizeof(float));            // 2 MB
  size_t binned_end = off;
  size_t o_qcnt   = alloc((size_t)NQBINS * sizeof(int));         // 128 KB
  size_t o_qcur   = alloc((size_t)NQBINS * sizeof(int));         // 128 KB
  size_t o_qs     = alloc((size_t)M * 3 * sizeof(float));        // 6 MB
  size_t o_qidx   = alloc((size_t)M * sizeof(int));              // 2 MB
  size_t o_dcc    = alloc((size_t)M * 8 * sizeof(float));        // 16 MB
  size_t full_end = off;

  float*  grid   = (float*)(W + o_grid);
  int*    cnt    = (int*)(W + o_cnt);
  int*    offs   = (int*)(W + o_offs);
  int*    cursor = (int*)(W + o_cursor);
  int*    bsum   = (int*)(W + o_bsum);
  float4* pf     = (float4*)(W + o_pf);
  float4* pu     = (float4*)(W + o_pu);
  float*  pz     = (float*)(W + o_pz);
  int*    qcnt   = (int*)(W + o_qcnt);
  int*    qcur   = (int*)(W + o_qcur);
  float*  qs     = (float*)(W + o_qs);
  int*    qidx   = (int*)(W + o_qidx);
  float*  dcc    = (float*)(W + o_dcc);

  // ---- grid construction ----
  if (binned_end <= ws_size) {
    hipMemsetAsync(cnt, 0, (size_t)NCELLS * sizeof(int), stream);
    hist_kernel<<<(N+255)/256, 256, 0, stream>>>(xsr, cnt, N);
    scan1_kernel<<<SCAN_BLOCKS, 256, 0, stream>>>(cnt, offs, bsum);
    scan2_kernel<<<1, 1024, 0, stream>>>(bsum);
    scan3_kernel<<<NCELLS/256, 256, 0, stream>>>(offs, bsum, cursor);
    scatter_kernel<<<(N+255)/256, 256, 0, stream>>>(xsr, xsc, Wf, bf, cursor, pf, pu, pz, N);
    p2g_gather_pair_kernel<<<(NCELLS/2)/256, 256, 0, stream>>>(offs, pf, pu, pz, grid);
  } else {
    hipMemsetAsync(grid, 0, (size_t)NCELLS * 8 * sizeof(float), stream);
    p2g_atomic_kernel<<<(N+255)/256, 256, 0, stream>>>(xsr, xsc, Wf, bf, grid, N);
  }

  // ---- query ordering (sorted if space permits, else identity) ----
  if (full_end <= ws_size) {
    hipMemsetAsync(qcnt, 0, (size_t)NQBINS * sizeof(int), stream);
    qhist_kernel<<<(M+255)/256, 256, 0, stream>>>(xq, qcnt, M);
    qscan_kernel<<<1, 1024, 0, stream>>>(qcnt, qcur);
    qscatter_kernel<<<(M+255)/256, 256, 0, stream>>>(xq, qcur, qs, qidx, M);
  } else {
    qident_kernel<<<(M+255)/256, 256, 0, stream>>>(xq, qs, qidx, M);
  }

  // ---- two-pass gather + MLP ----
  int nblk = (M + 255) / 256;
  gather_pass_kernel<<<nblk, 256, 0, stream>>>(qs, qidx, grid, dcc, M, nblk);
  mlp_pass_kernel<<<nblk, 256, 0, stream>>>(qs, qidx, dcc, W1,b1,W2,b2,W3,b3, out, M);
}

// Round 10
// 418.941 us; speedup vs baseline: 1.3173x; 1.3173x over previous
//
#include <hip/hip_runtime.h>
#include <cstdint>

#ifndef JAX_PARTITIONABLE
#define JAX_PARTITIONABLE 1   // modern JAX (>=0.5) default threefry_partitionable
#endif

#define NCELLS (128*128*128)          // 2,097,152
#define SCAN_BLOCKS 1024              // NCELLS / 2048
#define NQBINS (32*32*32)             // coarse query bins (4x4x4 cells each)

// ---------------- Threefry-2x32, key = (0, 42)  (jax.random.key(42)) ----------------
__device__ __forceinline__ uint32_t rotl32(uint32_t v, int s){ return (v << s) | (v >> (32 - s)); }

__device__ __forceinline__ void tf2x32(uint32_t& x0, uint32_t& x1){
  const uint32_t k0 = 0u, k1 = 42u;
  const uint32_t k2 = 0x1BD11BDAu ^ k0 ^ k1;
  x0 += k0; x1 += k1;
#define TFR(r) { x0 += x1; x1 = rotl32(x1,(r)); x1 ^= x0; }
  TFR(13) TFR(15) TFR(26) TFR(6)
  x0 += k1; x1 += k2 + 1u;
  TFR(17) TFR(29) TFR(16) TFR(24)
  x0 += k2; x1 += k0 + 2u;
  TFR(13) TFR(15) TFR(26) TFR(6)
  x0 += k0; x1 += k1 + 3u;
  TFR(17) TFR(29) TFR(16) TFR(24)
  x0 += k1; x1 += k2 + 4u;
  TFR(13) TFR(15) TFR(26) TFR(6)
  x0 += k2; x1 += k0 + 5u;
#undef TFR
}

// XLA f32 ErfInv (Giles) — exact coefficient match with jax/XLA
__device__ __forceinline__ float erfinv_xla(float x){
  float w = -log1pf(-x*x);
  float p;
  if (w < 5.0f){
    w -= 2.5f;
    p =  2.81022636e-08f;
    p = fmaf(p,w, 3.43273939e-07f);
    p = fmaf(p,w,-3.5233877e-06f);
    p = fmaf(p,w,-4.39150654e-06f);
    p = fmaf(p,w, 0.00021858087f);
    p = fmaf(p,w,-0.00125372503f);
    p = fmaf(p,w,-0.00417768164f);
    p = fmaf(p,w, 0.246640727f);
    p = fmaf(p,w, 1.50140941f);
  } else {
    w = sqrtf(w) - 3.0f;
    p = -0.000200214257f;
    p = fmaf(p,w, 0.000100950558f);
    p = fmaf(p,w, 0.00134934322f);
    p = fmaf(p,w,-0.00367342844f);
    p = fmaf(p,w, 0.00573950773f);
    p = fmaf(p,w,-0.0076224613f);
    p = fmaf(p,w, 0.00943887047f);
    p = fmaf(p,w, 1.00167406f);
    p = fmaf(p,w, 2.83297682f);
  }
  return p*x;
}

// noise[i] = 0.8 * sqrt(2)*erfinv(uniform(-1,1)) with jax bit semantics
__device__ __forceinline__ float noise_at(uint32_t idx, uint32_t half){
#if JAX_PARTITIONABLE
  (void)half;
  uint32_t x0 = 0u, x1 = idx;     // counter = (hi=0, lo=i)
  tf2x32(x0, x1);
  uint32_t bits = x0 ^ x1;        // partitionable 32-bit path: xor-fold of both words
#else
  uint32_t j  = (idx < half) ? idx : (idx - half);
  uint32_t x0 = j, x1 = j + half;
  tf2x32(x0, x1);
  uint32_t bits = (idx < half) ? x0 : x1;
#endif
  float f = __uint_as_float((bits >> 9) | 0x3f800000u) - 1.0f;      // [0,1)
  float u = fmaxf(-0.99999994f, fmaf(f, 2.0f, -0.99999994f));       // (-1,1)
  return (1.41421356f * erfinv_xla(u)) * 0.8f;
}

// jax.nn.gelu approximate=True
__device__ __forceinline__ float tanh_fast(float x){
  float e = __expf(2.0f * x);
  return 1.0f - 2.0f * __builtin_amdgcn_rcpf(e + 1.0f);
}
__device__ __forceinline__ float gelu_f(float x){
  float inner = 0.7978845608028654f * (x + 0.044715f*(x*x*x));
  return 0.5f * x * (1.0f + tanh_fast(inner));
}

// common per-particle geometry
__device__ __forceinline__ void particle_cell(const float* xsr, int i,
                                              float& sx, float& sy, float& sz,
                                              int& bx, int& by, int& bz,
                                              float& dx, float& dy, float& dz){
  sx = fminf(fmaxf(xsr[3*i+0], 0.0f), 1.0f);
  sy = fminf(fmaxf(xsr[3*i+1], 0.0f), 1.0f);
  sz = fminf(fmaxf(xsr[3*i+2], 0.0f), 1.0f);
  float cx = fminf(fmaxf(sx*127.0f, 0.0f), 126.999f);
  float cy = fminf(fmaxf(sy*127.0f, 0.0f), 126.999f);
  float cz = fminf(fmaxf(sz*127.0f, 0.0f), 126.999f);
  float bxf = floorf(cx), byf = floorf(cy), bzf = floorf(cz);
  bx = (int)bxf; by = (int)byf; bz = (int)bzf;
  dx = cx - bxf; dy = cy - byf; dz = cz - bzf;
}

__device__ __forceinline__ int qbin_of(float qx01, float qy01, float qz01){
  int bx = min((int)(qx01*127.0f), 127) >> 2;
  int by = min((int)(qy01*127.0f), 127) >> 2;
  int bz = min((int)(qz01*127.0f), 127) >> 2;
  return (((bx<<5)+by)<<5)+bz;
}

// ---------------- fused histogram: particle cells + query coarse bins ----------------
__global__ void __launch_bounds__(256) hist2_kernel(
    const float* __restrict__ xsr, const float* __restrict__ xq,
    int* __restrict__ cnt, int* __restrict__ qcnt, int N, int M){
  int i = blockIdx.x*256 + threadIdx.x;
  if (i < N){
    float sx,sy,sz,dx,dy,dz; int bx,by,bz;
    particle_cell(xsr,i,sx,sy,sz,bx,by,bz,dx,dy,dz);
    atomicAdd(&cnt[(((bx<<7)+by)<<7)+bz], 1);
  }
  if (i < M){
    float qx01 = fminf(fmaxf(xq[3*i+0], 0.0f), 1.0f);
    float qy01 = fminf(fmaxf(xq[3*i+1], 0.0f), 1.0f);
    float qz01 = fminf(fmaxf(xq[3*i+2], 0.0f), 1.0f);
    atomicAdd(&qcnt[qbin_of(qx01,qy01,qz01)], 1);
  }
}

// exclusive scan stage 1: 1024 blocks x 256 thr x 8 elems
__global__ void __launch_bounds__(256) scan1_kernel(const int* __restrict__ cnt,
                                                    int* __restrict__ offs,
                                                    int* __restrict__ bsum){
  __shared__ int lds[256];
  int t = threadIdx.x;
  int base = blockIdx.x*2048 + t*8;
  const int4* c4 = reinterpret_cast<const int4*>(cnt + base);
  int4 a0 = c4[0], a1 = c4[1];
  int s = a0.x+a0.y+a0.z+a0.w + a1.x+a1.y+a1.z+a1.w;
  lds[t] = s; __syncthreads();
  for (int off = 1; off < 256; off <<= 1){
    int v = (t >= off) ? lds[t-off] : 0;
    __syncthreads();
    lds[t] += v;
    __syncthreads();
  }
  int run = lds[t] - s;               // exclusive prefix of this thread's chunk
  if (t == 255) bsum[blockIdx.x] = lds[255];
  int* o = offs + base;
  o[0]=run; run+=a0.x; o[1]=run; run+=a0.y; o[2]=run; run+=a0.z; o[3]=run; run+=a0.w;
  o[4]=run; run+=a1.x; o[5]=run; run+=a1.y; o[6]=run; run+=a1.z; o[7]=run;
}

// fused: scan block sums (particles) + full exclusive scan of 32K query-bin counts
__global__ void __launch_bounds__(1024) scan2q_kernel(int* __restrict__ bsum,
                                                      const int* __restrict__ qcnt,
                                                      int* __restrict__ qcur){
  __shared__ int lds[1024];
  int t = threadIdx.x;
  // part 1: particle block sums
  int v = bsum[t];
  lds[t] = v; __syncthreads();
  for (int off = 1; off < 1024; off <<= 1){
    int u = (t >= off) ? lds[t-off] : 0;
    __syncthreads();
    lds[t] += u;
    __syncthreads();
  }
  bsum[t] = lds[t] - v;
  if (t == 1023) bsum[1024] = lds[1023];
  __syncthreads();
  // part 2: query coarse-bin scan (32 elems/thread)
  int base = t*32;
  int loc[32];
  int s = 0;
#pragma unroll
  for (int j = 0; j < 32; ++j){ loc[j] = qcnt[base+j]; s += loc[j]; }
  lds[t] = s; __syncthreads();
  for (int off = 1; off < 1024; off <<= 1){
    int u = (t >= off) ? lds[t-off] : 0;
    __syncthreads();
    lds[t] += u;
    __syncthreads();
  }
  int run = lds[t] - s;
#pragma unroll
  for (int j = 0; j < 32; ++j){ qcur[base+j] = run; run += loc[j]; }
}

// stage 3: add block offsets, init cursor, write sentinel
__global__ void __launch_bounds__(256) scan3_kernel(int* __restrict__ offs,
                                                    const int* __restrict__ bsum,
                                                    int* __restrict__ cursor){
  int i = blockIdx.x*256 + threadIdx.x;     // exactly NCELLS threads
  int o = offs[i] + bsum[i >> 11];
  offs[i] = o; cursor[i] = o;
  if (i == 0) offs[NCELLS] = bsum[SCAN_BLOCKS];
}

// fused scatter: particle payload bump-alloc + query coarse-sorted stash
__global__ void __launch_bounds__(256) scatter2_kernel(
    const float* __restrict__ xsr, const float* __restrict__ xsc,
    const float* __restrict__ Wf,  const float* __restrict__ bf,
    const float* __restrict__ xq,
    int* __restrict__ cursor, int* __restrict__ qcur,
    float4* __restrict__ pf, float4* __restrict__ pu, float* __restrict__ pz,
    float* __restrict__ qs, int* __restrict__ qidx, int N, int M){
  int i = blockIdx.x*256 + threadIdx.x;
  if (i < N){
    float sx,sy,sz,dx,dy,dz; int bx,by,bz;
    particle_cell(xsr,i,sx,sy,sz,bx,by,bz,dx,dy,dz);
    float ux = xsc[3*i+0] - sx;
    float uy = xsc[3*i+1] - sy;
    float uz = xsc[3*i+2] - sz;
    float f0 = gelu_f(ux*Wf[0] + uy*Wf[3] + uz*Wf[6] + bf[0]);
    float f1 = gelu_f(ux*Wf[1] + uy*Wf[4] + uz*Wf[7] + bf[1]);
    float f2 = gelu_f(ux*Wf[2] + uy*Wf[5] + uz*Wf[8] + bf[2]);
    int bin = (((bx<<7)+by)<<7)+bz;
    int pos = atomicAdd(&cursor[bin], 1);
    pf[pos] = make_float4(f0, f1, f2, dx);
    pu[pos] = make_float4(ux, uy, uz, dy);
    pz[pos] = dz;
  }
  if (i < M){
    float qx01 = fminf(fmaxf(xq[3*i+0], 0.0f), 1.0f);
    float qy01 = fminf(fmaxf(xq[3*i+1], 0.0f), 1.0f);
    float qz01 = fminf(fmaxf(xq[3*i+2], 0.0f), 1.0f);
    int pos = atomicAdd(&qcur[qbin_of(qx01,qy01,qz01)], 1);
    qs[3*pos+0] = qx01; qs[3*pos+1] = qy01; qs[3*pos+2] = qz01;
    qidx[pos] = i;
  }
}

// z-pair per-cell gather: thread owns cells (x,y,z0) and (x,y,z0+1), z0 even.
__global__ void __launch_bounds__(256) p2g_gather_pair_kernel(
    const int* __restrict__ offs,
    const float4* __restrict__ pf, const float4* __restrict__ pu,
    const float* __restrict__ pz, float* __restrict__ grid){
  int tid = blockIdx.x*256 + threadIdx.x;   // exactly NCELLS/2 threads
  int zg = tid & 63, y = (tid >> 6) & 127, x = tid >> 13;
  int z0 = zg << 1;
  float a0[2]={0,0},a1[2]={0,0},a2[2]={0,0},a3[2]={0,0},a4[2]={0,0},a5[2]={0,0},a6[2]={0,0};
#pragma unroll
  for (int ox = 0; ox < 2; ++ox){
    int bx = x - ox; if (bx < 0) continue;
#pragma unroll
    for (int oy = 0; oy < 2; ++oy){
      int by = y - oy; if (by < 0) continue;
      int b0 = ((((bx<<7)+by)<<7)) + z0;
      int em = offs[b0];
      int sm = (z0 > 0) ? offs[b0-1] : em;
      int e0 = offs[b0+1];
      int e1 = offs[b0+2];
      for (int p = sm; p < em; ++p){
        float4 A = pf[p]; float4 B = pu[p]; float dz = pz[p];
        float wx = ox ? A.w : 1.0f - A.w;
        float wy = oy ? B.w : 1.0f - B.w;
        float w = wx*wy*dz;
        a0[0]=fmaf(A.x,w,a0[0]); a1[0]=fmaf(A.y,w,a1[0]); a2[0]=fmaf(A.z,w,a2[0]);
        a3[0]+=w; a4[0]=fmaf(B.x,w,a4[0]); a5[0]=fmaf(B.y,w,a5[0]); a6[0]=fmaf(B.z,w,a6[0]);
      }
      for (int p = em; p < e0; ++p){
        float4 A = pf[p]; float4 B = pu[p]; float dz = pz[p];
        float wx = ox ? A.w : 1.0f - A.w;
        float wy = oy ? B.w : 1.0f - B.w;
        float wxy = wx*wy;
        float w0 = wxy*(1.0f-dz), w1 = wxy*dz;
        a0[0]=fmaf(A.x,w0,a0[0]); a1[0]=fmaf(A.y,w0,a1[0]); a2[0]=fmaf(A.z,w0,a2[0]);
        a3[0]+=w0; a4[0]=fmaf(B.x,w0,a4[0]); a5[0]=fmaf(B.y,w0,a5[0]); a6[0]=fmaf(B.z,w0,a6[0]);
        a0[1]=fmaf(A.x,w1,a0[1]); a1[1]=fmaf(A.y,w1,a1[1]); a2[1]=fmaf(A.z,w1,a2[1]);
        a3[1]+=w1; a4[1]=fmaf(B.x,w1,a4[1]); a5[1]=fmaf(B.y,w1,a5[1]); a6[1]=fmaf(B.z,w1,a6[1]);
      }
      for (int p = e0; p < e1; ++p){
        float4 A = pf[p]; float4 B = pu[p]; float dz = pz[p];
        float wx = ox ? A.w : 1.0f - A.w;
        float wy = oy ? B.w : 1.0f - B.w;
        float w = wx*wy*(1.0f-dz);
        a0[1]=fmaf(A.x,w,a0[1]); a1[1]=fmaf(A.y,w,a1[1]); a2[1]=fmaf(A.z,w,a2[1]);
        a3[1]+=w; a4[1]=fmaf(B.x,w,a4[1]); a5[1]=fmaf(B.y,w,a5[1]); a6[1]=fmaf(B.z,w,a6[1]);
      }
    }
  }
  int cell0 = ((((x<<7)+y)<<7)) + z0;
  float4* g = reinterpret_cast<float4*>(grid + ((size_t)cell0 << 3));
  g[0] = make_float4(a0[0],a1[0],a2[0],a3[0]);
  g[1] = make_float4(a4[0],a5[0],a6[0],0.0f);
  g[2] = make_float4(a0[1],a1[1],a2[1],a3[1]);
  g[3] = make_float4(a4[1],a5[1],a6[1],0.0f);
}

// ---------------- fused gather + MLP (R5 structure: LDS row staging, VGPR 64) ----------------
__device__ __forceinline__ void gather_mlp_body(
    int m, float qx01, float qy01, float qz01, float* row,
    const float* __restrict__ grid,
    const float* __restrict__ W1,  const float* __restrict__ b1,
    const float* __restrict__ W2,  const float* __restrict__ b2,
    const float* __restrict__ W3,  const float* __restrict__ b3,
    float* __restrict__ out, int M)
{
  float qx = qx01*127.0f, qy = qy01*127.0f, qz = qz01*127.0f;

  float r0=0.f,r1=0.f,r2=0.f,r3=0.f,r4=0.f,r5=0.f,r6=0.f;
  const uint32_t KSTRIDE = 3u*(uint32_t)M;
  const uint32_t HALF    = 4u*KSTRIDE;
  uint32_t m3 = 3u*(uint32_t)m;

  for (int k = 0; k < 8; ++k) {
    uint32_t base = (uint32_t)k*KSTRIDE + m3;
    float px = qx + noise_at(base+0u, HALF);
    float py = qy + noise_at(base+1u, HALF);
    float pz = qz + noise_at(base+2u, HALF);
    float fxf = floorf(px), fyf = floorf(py), fzf = floorf(pz);
    float fx = px - fxf, fy = py - fyf, fz = pz - fzf;
    int lx = (int)fxf, ly = (int)fyf, lz = (int)fzf;
    int x0i = min(max(lx,0),127),   x1i = min(max(lx+1,0),127);
    int y0i = min(max(ly,0),127),   y1i = min(max(ly+1,0),127);
    int z0i = min(max(lz,0),127),   z1i = min(max(lz+1,0),127);
    float ex = 1.0f-fx, ey = 1.0f-fy, ez = 1.0f-fz;

    auto corner = [&](int xi,int yi,int zi,float w){
      const float4* p = reinterpret_cast<const float4*>(grid + ((size_t)((((xi<<7)+yi)<<7)+zi) << 3));
      float4 g0 = p[0]; float4 g1 = p[1];
      r0 = fmaf(g0.x, w, r0); r1 = fmaf(g0.y, w, r1); r2 = fmaf(g0.z, w, r2);
      r3 = fmaf(g0.w, w, r3); r4 = fmaf(g1.x, w, r4); r5 = fmaf(g1.y, w, r5);
      r6 = fmaf(g1.z, w, r6);
    };
    corner(x0i,y0i,z0i, ex*ey*ez);
    corner(x0i,y0i,z1i, ex*ey*fz);
    corner(x0i,y1i,z0i, ex*fy*ez);
    corner(x0i,y1i,z1i, ex*fy*fz);
    corner(x1i,y0i,z0i, fx*ey*ez);
    corner(x1i,y0i,z1i, fx*ey*fz);
    corner(x1i,y1i,z0i, fx*fy*ez);
    corner(x1i,y1i,z1i, fx*fy*fz);
  }

  float dmean = r3*0.125f;
  float denom = fmaxf(dmean, 1e-5f);
  float maskf = (dmean > 1e-5f) ? 1.0f : 0.0f;
  float fn0 = (r0*0.125f)/denom*maskf;
  float fn1 = (r1*0.125f)/denom*maskf;
  float fn2 = (r2*0.125f)/denom*maskf;
  float un0 = (r4*0.125f)/denom*maskf;
  float un1 = (r5*0.125f)/denom*maskf;
  float un2 = (r6*0.125f)/denom*maskf;

  float dec[24];
  dec[0]=fn0; dec[1]=fn1; dec[2]=fn2; dec[3]=un0; dec[4]=un1; dec[5]=un2;
  dec[6]  = __builtin_amdgcn_sinf(0.5f*qx01);   // v_sin input is revolutions
  dec[7]  = __builtin_amdgcn_sinf(0.5f*qy01);
  dec[8]  = __builtin_amdgcn_sinf(0.5f*qz01);
  dec[9]  = __builtin_amdgcn_cosf(0.5f*qx01);
  dec[10] = __builtin_amdgcn_cosf(0.5f*qy01);
  dec[11] = __builtin_amdgcn_cosf(0.5f*qz01);
  dec[12] = __builtin_amdgcn_sinf(qx01);
  dec[13] = __builtin_amdgcn_sinf(qy01);
  dec[14] = __builtin_amdgcn_sinf(qz01);
  dec[15] = __builtin_amdgcn_cosf(qx01);
  dec[16] = __builtin_amdgcn_cosf(qy01);
  dec[17] = __builtin_amdgcn_cosf(qz01);
  dec[18] = __builtin_amdgcn_sinf(2.0f*qx01);
  dec[19] = __builtin_amdgcn_sinf(2.0f*qy01);
  dec[20] = __builtin_amdgcn_sinf(2.0f*qz01);
  dec[21] = __builtin_amdgcn_cosf(2.0f*qx01);
  dec[22] = __builtin_amdgcn_cosf(2.0f*qy01);
  dec[23] = __builtin_amdgcn_cosf(2.0f*qz01);

#pragma unroll
  for (int k2 = 0; k2 < 24; ++k2) row[k2] = dec[k2];

  // layer 1: 24 -> 64
  float h[64];
#pragma unroll
  for (int j = 0; j < 64; ++j) h[j] = b1[j];
  for (int k2 = 0; k2 < 24; ++k2) {
    float dk = row[k2];
    const float* __restrict__ wr = W1 + (k2<<6);
#pragma unroll
    for (int j = 0; j < 64; ++j) h[j] = fmaf(dk, wr[j], h[j]);
  }

  // layer 2: 64 -> 64, h staged through LDS in two halves
  float g2[64];
#pragma unroll
  for (int j = 0; j < 64; ++j) g2[j] = b2[j];
#pragma unroll
  for (int j = 0; j < 32; ++j) row[j] = gelu_f(h[j]);
  for (int k2 = 0; k2 < 32; ++k2) {
    float hk = row[k2];
    const float* __restrict__ wr = W2 + (k2<<6);
#pragma unroll
    for (int j = 0; j < 64; ++j) g2[j] = fmaf(hk, wr[j], g2[j]);
  }
#pragma unroll
  for (int j = 0; j < 32; ++j) row[j] = gelu_f(h[j+32]);
  for (int k2 = 0; k2 < 32; ++k2) {
    float hk = row[k2];
    const float* __restrict__ wr = W2 + ((k2+32)<<6);
#pragma unroll
    for (int j = 0; j < 64; ++j) g2[j] = fmaf(hk, wr[j], g2[j]);
  }

  // layer 3: 64 -> 3
  float o0 = b3[0], o1 = b3[1], o2 = b3[2];
#pragma unroll
  for (int k2 = 0; k2 < 64; ++k2) {
    float g = gelu_f(g2[k2]);
    o0 = fmaf(g, W3[3*k2+0], o0);
    o1 = fmaf(g, W3[3*k2+1], o1);
    o2 = fmaf(g, W3[3*k2+2], o2);
  }

  out[3*m+0] = fminf(fmaxf(un0 + o0, 0.001f), 0.999f);
  out[3*m+1] = fminf(fmaxf(un1 + o1, 0.001f), 0.999f);
  out[3*m+2] = fminf(fmaxf(un2 + o2, 0.001f), 0.999f);
}

// sorted-order fused kernel: block b -> XCD-contiguous chunk of sorted queries
__global__ void __launch_bounds__(256) gather_mlp_sorted_kernel(
    const float* __restrict__ qs,  const int* __restrict__ qidx,
    const float* __restrict__ grid,
    const float* __restrict__ W1,  const float* __restrict__ b1,
    const float* __restrict__ W2,  const float* __restrict__ b2,
    const float* __restrict__ W3,  const float* __restrict__ b3,
    float* __restrict__ out, int M, int nblk)
{
  __shared__ float sh[256*33];   // per-thread 33-float row; stride 33 -> conflict-free
  int b = blockIdx.x;
  int nb8 = (nblk >> 3) << 3;
  int c = (b < nb8) ? ((b & 7)*(nblk >> 3) + (b >> 3)) : b;
  int t = c*256 + threadIdx.x;
  if (t >= M) return;
  float* row = sh + threadIdx.x*33;
  int m = qidx[t];
  gather_mlp_body(m, qs[3*t+0], qs[3*t+1], qs[3*t+2], row,
                  grid, W1,b1,W2,b2,W3,b3, out, M);
}

// ---------------- fallbacks (ws too small; not used in practice) ----------------
__global__ void __launch_bounds__(256) p2g_atomic_kernel(
    const float* __restrict__ xsr, const float* __restrict__ xsc,
    const float* __restrict__ Wf,  const float* __restrict__ bf,
    float* __restrict__ grid, int N)
{
  int i = blockIdx.x*256 + threadIdx.x;
  if (i >= N) return;
  float sx,sy,sz,dx,dy,dz; int bx,by,bz;
  particle_cell(xsr,i,sx,sy,sz,bx,by,bz,dx,dy,dz);
  float ux = xsc[3*i+0] - sx;
  float uy = xsc[3*i+1] - sy;
  float uz = xsc[3*i+2] - sz;
  float f0 = gelu_f(ux*Wf[0] + uy*Wf[3] + uz*Wf[6] + bf[0]);
  float f1 = gelu_f(ux*Wf[1] + uy*Wf[4] + uz*Wf[7] + bf[1]);
  float f2 = gelu_f(ux*Wf[2] + uy*Wf[5] + uz*Wf[8] + bf[2]);
  float ex = 1.0f - dx, ey = 1.0f - dy, ez = 1.0f - dz;
  auto splat = [&](int xi, int yi, int zi, float w){
    float* p = grid + ((size_t)((((xi<<7)+yi)<<7)+zi) << 3);
    unsafeAtomicAdd(p+0, f0*w);
    unsafeAtomicAdd(p+1, f1*w);
    unsafeAtomicAdd(p+2, f2*w);
    unsafeAtomicAdd(p+3, w);
    unsafeAtomicAdd(p+4, ux*w);
    unsafeAtomicAdd(p+5, uy*w);
    unsafeAtomicAdd(p+6, uz*w);
  };
  splat(bx,  by,  bz,   ex*ey*ez);
  splat(bx,  by,  bz+1, ex*ey*dz);
  splat(bx,  by+1,bz,   ex*dy*ez);
  splat(bx,  by+1,bz+1, ex*dy*dz);
  splat(bx+1,by,  bz,   dx*ey*ez);
  splat(bx+1,by,  bz+1, dx*ey*dz);
  splat(bx+1,by+1,bz,   dx*dy*ez);
  splat(bx+1,by+1,bz+1, dx*dy*dz);
}

__global__ void __launch_bounds__(256) qident_kernel(
    const float* __restrict__ xq, float* __restrict__ qs, int* __restrict__ qidx, int M){
  int i = blockIdx.x*256 + threadIdx.x;
  if (i >= M) return;
  qs[3*i+0] = fminf(fmaxf(xq[3*i+0], 0.0f), 1.0f);
  qs[3*i+1] = fminf(fmaxf(xq[3*i+1], 0.0f), 1.0f);
  qs[3*i+2] = fminf(fmaxf(xq[3*i+2], 0.0f), 1.0f);
  qidx[i] = i;
}

extern "C" void kernel_launch(void* const* d_in, const int* in_sizes, int n_in,
                              void* d_out, int out_size, void* d_ws, size_t ws_size,
                              hipStream_t stream)
{
  const float* xq  = (const float*)d_in[0];
  const float* xsr = (const float*)d_in[1];
  const float* xsc = (const float*)d_in[2];
  const float* Wf  = (const float*)d_in[3];
  const float* bf  = (const float*)d_in[4];
  const float* W1  = (const float*)d_in[5];
  const float* b1  = (const float*)d_in[6];
  const float* W2  = (const float*)d_in[7];
  const float* b2  = (const float*)d_in[8];
  const float* W3  = (const float*)d_in[9];
  const float* b3  = (const float*)d_in[10];
  float* out  = (float*)d_out;
  int M = in_sizes[0]/3;
  int N = in_sizes[1]/3;

  // workspace layout (256B-aligned chunks); cnt and qcnt adjacent -> single memset
  char* W = (char*)d_ws;
  size_t off = 0;
  auto alloc = [&](size_t bytes){ size_t o = off; off = (off + bytes + 255) & ~(size_t)255; return o; };
  size_t o_grid   = alloc((size_t)NCELLS * 8 * sizeof(float));   // 64 MiB
  size_t o_cnt    = alloc((size_t)NCELLS * sizeof(int));         // 8 MiB   (NCELLS*4 is 256-aligned)
  size_t o_qcnt   = alloc((size_t)NQBINS * sizeof(int));         // 128 KB  (directly after cnt)
  size_t o_offs   = alloc(((size_t)NCELLS + 1) * sizeof(int));   // 8 MiB
  size_t o_cursor = alloc((size_t)NCELLS * sizeof(int));         // 8 MiB
  size_t o_bsum   = alloc((size_t)(SCAN_BLOCKS + 1) * sizeof(int));
  size_t o_qcur   = alloc((size_t)NQBINS * sizeof(int));         // 128 KB
  size_t o_pf     = alloc((size_t)N * sizeof(float4));           // 8 MB
  size_t o_pu     = alloc((size_t)N * sizeof(float4));           // 8 MB
  size_t o_pz     = alloc((size_t)N * sizeof(float));            // 2 MB
  size_t o_qs     = alloc((size_t)M * 3 * sizeof(float));        // 6 MB
  size_t o_qidx   = alloc((size_t)M * sizeof(int));              // 2 MB
  size_t full_end = off;

  float*  grid   = (float*)(W + o_grid);
  int*    cnt    = (int*)(W + o_cnt);
  int*    qcnt   = (int*)(W + o_qcnt);
  int*    offs   = (int*)(W + o_offs);
  int*    cursor = (int*)(W + o_cursor);
  int*    bsum   = (int*)(W + o_bsum);
  int*    qcur   = (int*)(W + o_qcur);
  float4* pf     = (float4*)(W + o_pf);
  float4* pu     = (float4*)(W + o_pu);
  float*  pz     = (float*)(W + o_pz);
  float*  qs     = (float*)(W + o_qs);
  int*    qidx   = (int*)(W + o_qidx);

  int nthr = (N > M) ? N : M;
  int nblkNM = (nthr + 255) / 256;

  if (full_end <= ws_size) {
    // single memset covers cnt (8 MiB) + qcnt (128 KB) contiguously
    hipMemsetAsync(cnt, 0, (size_t)NCELLS * sizeof(int) + (size_t)NQBINS * sizeof(int), stream);
    hist2_kernel<<<nblkNM, 256, 0, stream>>>(xsr, xq, cnt, qcnt, N, M);
    scan1_kernel<<<SCAN_BLOCKS, 256, 0, stream>>>(cnt, offs, bsum);
    scan2q_kernel<<<1, 1024, 0, stream>>>(bsum, qcnt, qcur);
    scan3_kernel<<<NCELLS/256, 256, 0, stream>>>(offs, bsum, cursor);
    scatter2_kernel<<<nblkNM, 256, 0, stream>>>(xsr, xsc, Wf, bf, xq, cursor, qcur,
                                                pf, pu, pz, qs, qidx, N, M);
    p2g_gather_pair_kernel<<<(NCELLS/2)/256, 256, 0, stream>>>(offs, pf, pu, pz, grid);
  } else {
    // fallback: atomic p2g + identity query order (needs only grid+qs+qidx)
    hipMemsetAsync(grid, 0, (size_t)NCELLS * 8 * sizeof(float), stream);
    p2g_atomic_kernel<<<(N+255)/256, 256, 0, stream>>>(xsr, xsc, Wf, bf, grid, N);
    qident_kernel<<<(M+255)/256, 256, 0, stream>>>(xq, qs, qidx, M);
  }

  int nblk = (M + 255) / 256;
  gather_mlp_sorted_kernel<<<nblk, 256, 0, stream>>>(qs, qidx, grid, W1,b1,W2,b2,W3,b3, out, M, nblk);
}

// Round 11
// 409.966 us; speedup vs baseline: 1.3461x; 1.0219x over previous
//
#include <hip/hip_runtime.h>
#include <cstdint>

#ifndef JAX_PARTITIONABLE
#define JAX_PARTITIONABLE 1   // modern JAX (>=0.5) default threefry_partitionable
#endif

#define NCELLS (128*128*128)          // 2,097,152
#define SCAN_BLOCKS 1024              // NCELLS / 2048
#define NQBINS (32*32*32)             // coarse query bins (4x4x4 cells each)

typedef float v2f __attribute__((ext_vector_type(2)));

// ---------------- Threefry-2x32, key = (0, 42)  (jax.random.key(42)) ----------------
__device__ __forceinline__ uint32_t rotl32(uint32_t v, int s){ return (v << s) | (v >> (32 - s)); }

__device__ __forceinline__ void tf2x32(uint32_t& x0, uint32_t& x1){
  const uint32_t k0 = 0u, k1 = 42u;
  const uint32_t k2 = 0x1BD11BDAu ^ k0 ^ k1;
  x0 += k0; x1 += k1;
#define TFR(r) { x0 += x1; x1 = rotl32(x1,(r)); x1 ^= x0; }
  TFR(13) TFR(15) TFR(26) TFR(6)
  x0 += k1; x1 += k2 + 1u;
  TFR(17) TFR(29) TFR(16) TFR(24)
  x0 += k2; x1 += k0 + 2u;
  TFR(13) TFR(15) TFR(26) TFR(6)
  x0 += k0; x1 += k1 + 3u;
  TFR(17) TFR(29) TFR(16) TFR(24)
  x0 += k1; x1 += k2 + 4u;
  TFR(13) TFR(15) TFR(26) TFR(6)
  x0 += k2; x1 += k0 + 5u;
#undef TFR
}

// XLA f32 ErfInv (Giles) — exact coefficient match with jax/XLA
__device__ __forceinline__ float erfinv_xla(float x){
  float w = -log1pf(-x*x);
  float p;
  if (w < 5.0f){
    w -= 2.5f;
    p =  2.81022636e-08f;
    p = fmaf(p,w, 3.43273939e-07f);
    p = fmaf(p,w,-3.5233877e-06f);
    p = fmaf(p,w,-4.39150654e-06f);
    p = fmaf(p,w, 0.00021858087f);
    p = fmaf(p,w,-0.00125372503f);
    p = fmaf(p,w,-0.00417768164f);
    p = fmaf(p,w, 0.246640727f);
    p = fmaf(p,w, 1.50140941f);
  } else {
    w = sqrtf(w) - 3.0f;
    p = -0.000200214257f;
    p = fmaf(p,w, 0.000100950558f);
    p = fmaf(p,w, 0.00134934322f);
    p = fmaf(p,w,-0.00367342844f);
    p = fmaf(p,w, 0.00573950773f);
    p = fmaf(p,w,-0.0076224613f);
    p = fmaf(p,w, 0.00943887047f);
    p = fmaf(p,w, 1.00167406f);
    p = fmaf(p,w, 2.83297682f);
  }
  return p*x;
}

// noise[i] = 0.8 * sqrt(2)*erfinv(uniform(-1,1)) with jax bit semantics
__device__ __forceinline__ float noise_at(uint32_t idx, uint32_t half){
#if JAX_PARTITIONABLE
  (void)half;
  uint32_t x0 = 0u, x1 = idx;     // counter = (hi=0, lo=i)
  tf2x32(x0, x1);
  uint32_t bits = x0 ^ x1;        // partitionable 32-bit path: xor-fold of both words
#else
  uint32_t j  = (idx < half) ? idx : (idx - half);
  uint32_t x0 = j, x1 = j + half;
  tf2x32(x0, x1);
  uint32_t bits = (idx < half) ? x0 : x1;
#endif
  float f = __uint_as_float((bits >> 9) | 0x3f800000u) - 1.0f;      // [0,1)
  float u = fmaxf(-0.99999994f, fmaf(f, 2.0f, -0.99999994f));       // (-1,1)
  return (1.41421356f * erfinv_xla(u)) * 0.8f;
}

// jax.nn.gelu approximate=True
__device__ __forceinline__ float tanh_fast(float x){
  float e = __expf(2.0f * x);
  return 1.0f - 2.0f * __builtin_amdgcn_rcpf(e + 1.0f);
}
__device__ __forceinline__ float gelu_f(float x){
  float inner = 0.7978845608028654f * (x + 0.044715f*(x*x*x));
  return 0.5f * x * (1.0f + tanh_fast(inner));
}

// common per-particle geometry
__device__ __forceinline__ void particle_cell(const float* xsr, int i,
                                              float& sx, float& sy, float& sz,
                                              int& bx, int& by, int& bz,
                                              float& dx, float& dy, float& dz){
  sx = fminf(fmaxf(xsr[3*i+0], 0.0f), 1.0f);
  sy = fminf(fmaxf(xsr[3*i+1], 0.0f), 1.0f);
  sz = fminf(fmaxf(xsr[3*i+2], 0.0f), 1.0f);
  float cx = fminf(fmaxf(sx*127.0f, 0.0f), 126.999f);
  float cy = fminf(fmaxf(sy*127.0f, 0.0f), 126.999f);
  float cz = fminf(fmaxf(sz*127.0f, 0.0f), 126.999f);
  float bxf = floorf(cx), byf = floorf(cy), bzf = floorf(cz);
  bx = (int)bxf; by = (int)byf; bz = (int)bzf;
  dx = cx - bxf; dy = cy - byf; dz = cz - bzf;
}

__device__ __forceinline__ int qbin_of(float qx01, float qy01, float qz01){
  int bx = min((int)(qx01*127.0f), 127) >> 2;
  int by = min((int)(qy01*127.0f), 127) >> 2;
  int bz = min((int)(qz01*127.0f), 127) >> 2;
  return (((bx<<5)+by)<<5)+bz;
}

// ---------------- fused histogram: particle cells + query coarse bins ----------------
__global__ void __launch_bounds__(256) hist2_kernel(
    const float* __restrict__ xsr, const float* __restrict__ xq,
    int* __restrict__ cnt, int* __restrict__ qcnt, int N, int M){
  int i = blockIdx.x*256 + threadIdx.x;
  if (i < N){
    float sx,sy,sz,dx,dy,dz; int bx,by,bz;
    particle_cell(xsr,i,sx,sy,sz,bx,by,bz,dx,dy,dz);
    atomicAdd(&cnt[(((bx<<7)+by)<<7)+bz], 1);
  }
  if (i < M){
    float qx01 = fminf(fmaxf(xq[3*i+0], 0.0f), 1.0f);
    float qy01 = fminf(fmaxf(xq[3*i+1], 0.0f), 1.0f);
    float qz01 = fminf(fmaxf(xq[3*i+2], 0.0f), 1.0f);
    atomicAdd(&qcnt[qbin_of(qx01,qy01,qz01)], 1);
  }
}

// exclusive scan stage 1: 1024 blocks x 256 thr x 8 elems
__global__ void __launch_bounds__(256) scan1_kernel(const int* __restrict__ cnt,
                                                    int* __restrict__ offs,
                                                    int* __restrict__ bsum){
  __shared__ int lds[256];
  int t = threadIdx.x;
  int base = blockIdx.x*2048 + t*8;
  const int4* c4 = reinterpret_cast<const int4*>(cnt + base);
  int4 a0 = c4[0], a1 = c4[1];
  int s = a0.x+a0.y+a0.z+a0.w + a1.x+a1.y+a1.z+a1.w;
  lds[t] = s; __syncthreads();
  for (int off = 1; off < 256; off <<= 1){
    int v = (t >= off) ? lds[t-off] : 0;
    __syncthreads();
    lds[t] += v;
    __syncthreads();
  }
  int run = lds[t] - s;               // exclusive prefix of this thread's chunk
  if (t == 255) bsum[blockIdx.x] = lds[255];
  int* o = offs + base;
  o[0]=run; run+=a0.x; o[1]=run; run+=a0.y; o[2]=run; run+=a0.z; o[3]=run; run+=a0.w;
  o[4]=run; run+=a1.x; o[5]=run; run+=a1.y; o[6]=run; run+=a1.z; o[7]=run;
}

// fused: scan block sums (particles) + full exclusive scan of 32K query-bin counts
__global__ void __launch_bounds__(1024) scan2q_kernel(int* __restrict__ bsum,
                                                      const int* __restrict__ qcnt,
                                                      int* __restrict__ qcur){
  __shared__ int lds[1024];
  int t = threadIdx.x;
  int v = bsum[t];
  lds[t] = v; __syncthreads();
  for (int off = 1; off < 1024; off <<= 1){
    int u = (t >= off) ? lds[t-off] : 0;
    __syncthreads();
    lds[t] += u;
    __syncthreads();
  }
  bsum[t] = lds[t] - v;
  if (t == 1023) bsum[1024] = lds[1023];
  __syncthreads();
  int base = t*32;
  int loc[32];
  int s = 0;
#pragma unroll
  for (int j = 0; j < 32; ++j){ loc[j] = qcnt[base+j]; s += loc[j]; }
  lds[t] = s; __syncthreads();
  for (int off = 1; off < 1024; off <<= 1){
    int u = (t >= off) ? lds[t-off] : 0;
    __syncthreads();
    lds[t] += u;
    __syncthreads();
  }
  int run = lds[t] - s;
#pragma unroll
  for (int j = 0; j < 32; ++j){ qcur[base+j] = run; run += loc[j]; }
}

// stage 3: add block offsets, init cursor, write sentinel
__global__ void __launch_bounds__(256) scan3_kernel(int* __restrict__ offs,
                                                    const int* __restrict__ bsum,
                                                    int* __restrict__ cursor){
  int i = blockIdx.x*256 + threadIdx.x;     // exactly NCELLS threads
  int o = offs[i] + bsum[i >> 11];
  offs[i] = o; cursor[i] = o;
  if (i == 0) offs[NCELLS] = bsum[SCAN_BLOCKS];
}

// fused scatter: particle payload bump-alloc + query coarse-sorted stash
__global__ void __launch_bounds__(256) scatter2_kernel(
    const float* __restrict__ xsr, const float* __restrict__ xsc,
    const float* __restrict__ Wf,  const float* __restrict__ bf,
    const float* __restrict__ xq,
    int* __restrict__ cursor, int* __restrict__ qcur,
    float4* __restrict__ pf, float4* __restrict__ pu, float* __restrict__ pz,
    float* __restrict__ qs, int* __restrict__ qidx, int N, int M){
  int i = blockIdx.x*256 + threadIdx.x;
  if (i < N){
    float sx,sy,sz,dx,dy,dz; int bx,by,bz;
    particle_cell(xsr,i,sx,sy,sz,bx,by,bz,dx,dy,dz);
    float ux = xsc[3*i+0] - sx;
    float uy = xsc[3*i+1] - sy;
    float uz = xsc[3*i+2] - sz;
    float f0 = gelu_f(ux*Wf[0] + uy*Wf[3] + uz*Wf[6] + bf[0]);
    float f1 = gelu_f(ux*Wf[1] + uy*Wf[4] + uz*Wf[7] + bf[1]);
    float f2 = gelu_f(ux*Wf[2] + uy*Wf[5] + uz*Wf[8] + bf[2]);
    int bin = (((bx<<7)+by)<<7)+bz;
    int pos = atomicAdd(&cursor[bin], 1);
    pf[pos] = make_float4(f0, f1, f2, dx);
    pu[pos] = make_float4(ux, uy, uz, dy);
    pz[pos] = dz;
  }
  if (i < M){
    float qx01 = fminf(fmaxf(xq[3*i+0], 0.0f), 1.0f);
    float qy01 = fminf(fmaxf(xq[3*i+1], 0.0f), 1.0f);
    float qz01 = fminf(fmaxf(xq[3*i+2], 0.0f), 1.0f);
    int pos = atomicAdd(&qcur[qbin_of(qx01,qy01,qz01)], 1);
    qs[3*pos+0] = qx01; qs[3*pos+1] = qy01; qs[3*pos+2] = qz01;
    qidx[pos] = i;
  }
}

// z-pair per-cell gather: thread owns cells (x,y,z0) and (x,y,z0+1), z0 even.
// Single contiguous loop [sm,e1) per (ox,oy); branchless zone weights.
__global__ void __launch_bounds__(256) p2g_gather_pair_kernel(
    const int* __restrict__ offs,
    const float4* __restrict__ pf, const float4* __restrict__ pu,
    const float* __restrict__ pz, float* __restrict__ grid){
  int tid = blockIdx.x*256 + threadIdx.x;   // exactly NCELLS/2 threads
  int zg = tid & 63, y = (tid >> 6) & 127, x = tid >> 13;
  int z0 = zg << 1;
  float a0[2]={0,0},a1[2]={0,0},a2[2]={0,0},a3[2]={0,0},a4[2]={0,0},a5[2]={0,0},a6[2]={0,0};
#pragma unroll
  for (int ox = 0; ox < 2; ++ox){
    int bx = x - ox; if (bx < 0) continue;
#pragma unroll
    for (int oy = 0; oy < 2; ++oy){
      int by = y - oy; if (by < 0) continue;
      int b0 = ((((bx<<7)+by)<<7)) + z0;
      int em = offs[b0];                    // start of bin z0
      int sm = (z0 > 0) ? offs[b0-1] : em;  // start of bin z0-1
      int e0 = offs[b0+1];                  // start of bin z0+1
      int e1 = offs[b0+2];                  // end   of bin z0+1
      for (int p = sm; p < e1; ++p){
        float4 A = pf[p]; float4 B = pu[p]; float dz = pz[p];
        float wx = ox ? A.w : 1.0f - A.w;
        float wy = oy ? B.w : 1.0f - B.w;
        float wxy = wx*wy;
        // zone: p<em -> bin z0-1 (w0=dz, w1=0); p<e0 -> bin z0 (w0=1-dz, w1=dz); else bin z0+1 (w0=0, w1=1-dz)
        float omdz = 1.0f - dz;
        float w0 = (p < em) ? dz : ((p < e0) ? omdz : 0.0f);
        float w1 = (p < em) ? 0.0f : ((p < e0) ? dz : omdz);
        w0 *= wxy; w1 *= wxy;
        a0[0]=fmaf(A.x,w0,a0[0]); a1[0]=fmaf(A.y,w0,a1[0]); a2[0]=fmaf(A.z,w0,a2[0]);
        a3[0]+=w0; a4[0]=fmaf(B.x,w0,a4[0]); a5[0]=fmaf(B.y,w0,a5[0]); a6[0]=fmaf(B.z,w0,a6[0]);
        a0[1]=fmaf(A.x,w1,a0[1]); a1[1]=fmaf(A.y,w1,a1[1]); a2[1]=fmaf(A.z,w1,a2[1]);
        a3[1]+=w1; a4[1]=fmaf(B.x,w1,a4[1]); a5[1]=fmaf(B.y,w1,a5[1]); a6[1]=fmaf(B.z,w1,a6[1]);
      }
    }
  }
  int cell0 = ((((x<<7)+y)<<7)) + z0;
  float4* g = reinterpret_cast<float4*>(grid + ((size_t)cell0 << 3));
  g[0] = make_float4(a0[0],a1[0],a2[0],a3[0]);
  g[1] = make_float4(a4[0],a5[0],a6[0],0.0f);
  g[2] = make_float4(a0[1],a1[1],a2[1],a3[1]);
  g[3] = make_float4(a4[1],a5[1],a6[1],0.0f);
}

// ---------------- fused gather + MLP (packed v2f FMAs -> v_pk_fma_f32) ----------------
__device__ __forceinline__ void gather_mlp_body(
    int m, float qx01, float qy01, float qz01, float* row,
    const float* __restrict__ grid,
    const float* __restrict__ W1,  const float* __restrict__ b1,
    const float* __restrict__ W2,  const float* __restrict__ b2,
    const float* __restrict__ W3,  const float* __restrict__ b3,
    float* __restrict__ out, int M)
{
  float qx = qx01*127.0f, qy = qy01*127.0f, qz = qz01*127.0f;

  float r0=0.f,r1=0.f,r2=0.f,r3=0.f,r4=0.f,r5=0.f,r6=0.f;
  const uint32_t KSTRIDE = 3u*(uint32_t)M;
  const uint32_t HALF    = 4u*KSTRIDE;
  uint32_t m3 = 3u*(uint32_t)m;

  for (int k = 0; k < 8; ++k) {
    uint32_t base = (uint32_t)k*KSTRIDE + m3;
    float px = qx + noise_at(base+0u, HALF);
    float py = qy + noise_at(base+1u, HALF);
    float pz = qz + noise_at(base+2u, HALF);
    float fxf = floorf(px), fyf = floorf(py), fzf = floorf(pz);
    float fx = px - fxf, fy = py - fyf, fz = pz - fzf;
    int lx = (int)fxf, ly = (int)fyf, lz = (int)fzf;
    int x0i = min(max(lx,0),127),   x1i = min(max(lx+1,0),127);
    int y0i = min(max(ly,0),127),   y1i = min(max(ly+1,0),127);
    int z0i = min(max(lz,0),127),   z1i = min(max(lz+1,0),127);
    float ex = 1.0f-fx, ey = 1.0f-fy, ez = 1.0f-fz;

    auto corner = [&](int xi,int yi,int zi,float w){
      const float4* p = reinterpret_cast<const float4*>(grid + ((size_t)((((xi<<7)+yi)<<7)+zi) << 3));
      float4 g0 = p[0]; float4 g1 = p[1];
      r0 = fmaf(g0.x, w, r0); r1 = fmaf(g0.y, w, r1); r2 = fmaf(g0.z, w, r2);
      r3 = fmaf(g0.w, w, r3); r4 = fmaf(g1.x, w, r4); r5 = fmaf(g1.y, w, r5);
      r6 = fmaf(g1.z, w, r6);
    };
    corner(x0i,y0i,z0i, ex*ey*ez);
    corner(x0i,y0i,z1i, ex*ey*fz);
    corner(x0i,y1i,z0i, ex*fy*ez);
    corner(x0i,y1i,z1i, ex*fy*fz);
    corner(x1i,y0i,z0i, fx*ey*ez);
    corner(x1i,y0i,z1i, fx*ey*fz);
    corner(x1i,y1i,z0i, fx*fy*ez);
    corner(x1i,y1i,z1i, fx*fy*fz);
  }

  float dmean = r3*0.125f;
  float denom = fmaxf(dmean, 1e-5f);
  float maskf = (dmean > 1e-5f) ? 1.0f : 0.0f;
  float fn0 = (r0*0.125f)/denom*maskf;
  float fn1 = (r1*0.125f)/denom*maskf;
  float fn2 = (r2*0.125f)/denom*maskf;
  float un0 = (r4*0.125f)/denom*maskf;
  float un1 = (r5*0.125f)/denom*maskf;
  float un2 = (r6*0.125f)/denom*maskf;

  float dec[24];
  dec[0]=fn0; dec[1]=fn1; dec[2]=fn2; dec[3]=un0; dec[4]=un1; dec[5]=un2;
  dec[6]  = __builtin_amdgcn_sinf(0.5f*qx01);   // v_sin input is revolutions
  dec[7]  = __builtin_amdgcn_sinf(0.5f*qy01);
  dec[8]  = __builtin_amdgcn_sinf(0.5f*qz01);
  dec[9]  = __builtin_amdgcn_cosf(0.5f*qx01);
  dec[10] = __builtin_amdgcn_cosf(0.5f*qy01);
  dec[11] = __builtin_amdgcn_cosf(0.5f*qz01);
  dec[12] = __builtin_amdgcn_sinf(qx01);
  dec[13] = __builtin_amdgcn_sinf(qy01);
  dec[14] = __builtin_amdgcn_sinf(qz01);
  dec[15] = __builtin_amdgcn_cosf(qx01);
  dec[16] = __builtin_amdgcn_cosf(qy01);
  dec[17] = __builtin_amdgcn_cosf(qz01);
  dec[18] = __builtin_amdgcn_sinf(2.0f*qx01);
  dec[19] = __builtin_amdgcn_sinf(2.0f*qy01);
  dec[20] = __builtin_amdgcn_sinf(2.0f*qz01);
  dec[21] = __builtin_amdgcn_cosf(2.0f*qx01);
  dec[22] = __builtin_amdgcn_cosf(2.0f*qy01);
  dec[23] = __builtin_amdgcn_cosf(2.0f*qz01);

#pragma unroll
  for (int k2 = 0; k2 < 24; ++k2) row[k2] = dec[k2];

  // layer 1: 24 -> 64, packed 2-wide (v_pk_fma_f32): h2[32] v2f accumulators
  v2f h2[32];
  const v2f* b1v = reinterpret_cast<const v2f*>(b1);
#pragma unroll
  for (int j = 0; j < 32; ++j) h2[j] = b1v[j];
  for (int k2 = 0; k2 < 24; ++k2) {
    float dk = row[k2];
    v2f dk2; dk2.x = dk; dk2.y = dk;
    const v2f* wr2 = reinterpret_cast<const v2f*>(W1 + (k2<<6));
#pragma unroll
    for (int j = 0; j < 32; ++j) h2[j] = __builtin_elementwise_fma(wr2[j], dk2, h2[j]);
  }

  // layer 2: 64 -> 64 packed; gelu(h) staged through LDS in two halves
  v2f g2[32];
  const v2f* b2v = reinterpret_cast<const v2f*>(b2);
#pragma unroll
  for (int j = 0; j < 32; ++j) g2[j] = b2v[j];
#pragma unroll
  for (int j = 0; j < 16; ++j) { row[2*j] = gelu_f(h2[j].x); row[2*j+1] = gelu_f(h2[j].y); }
  for (int k2 = 0; k2 < 32; ++k2) {
    float hk = row[k2];
    v2f hk2; hk2.x = hk; hk2.y = hk;
    const v2f* wr2 = reinterpret_cast<const v2f*>(W2 + (k2<<6));
#pragma unroll
    for (int j = 0; j < 32; ++j) g2[j] = __builtin_elementwise_fma(wr2[j], hk2, g2[j]);
  }
#pragma unroll
  for (int j = 0; j < 16; ++j) { row[2*j] = gelu_f(h2[j+16].x); row[2*j+1] = gelu_f(h2[j+16].y); }
  for (int k2 = 0; k2 < 32; ++k2) {
    float hk = row[k2];
    v2f hk2; hk2.x = hk; hk2.y = hk;
    const v2f* wr2 = reinterpret_cast<const v2f*>(W2 + ((k2+32)<<6));
#pragma unroll
    for (int j = 0; j < 32; ++j) g2[j] = __builtin_elementwise_fma(wr2[j], hk2, g2[j]);
  }

  // layer 3: 64 -> 3 via components
  float o0 = b3[0], o1 = b3[1], o2 = b3[2];
#pragma unroll
  for (int j = 0; j < 32; ++j) {
    float ga = gelu_f(g2[j].x);
    float gb = gelu_f(g2[j].y);
    int ca = 2*j, cb = 2*j+1;
    o0 = fmaf(ga, W3[3*ca+0], o0); o1 = fmaf(ga, W3[3*ca+1], o1); o2 = fmaf(ga, W3[3*ca+2], o2);
    o0 = fmaf(gb, W3[3*cb+0], o0); o1 = fmaf(gb, W3[3*cb+1], o1); o2 = fmaf(gb, W3[3*cb+2], o2);
  }

  out[3*m+0] = fminf(fmaxf(un0 + o0, 0.001f), 0.999f);
  out[3*m+1] = fminf(fmaxf(un1 + o1, 0.001f), 0.999f);
  out[3*m+2] = fminf(fmaxf(un2 + o2, 0.001f), 0.999f);
}

// sorted-order fused kernel: block b -> XCD-contiguous chunk of sorted queries
__global__ void __launch_bounds__(256) gather_mlp_sorted_kernel(
    const float* __restrict__ qs,  const int* __restrict__ qidx,
    const float* __restrict__ grid,
    const float* __restrict__ W1,  const float* __restrict__ b1,
    const float* __restrict__ W2,  const float* __restrict__ b2,
    const float* __restrict__ W3,  const float* __restrict__ b3,
    float* __restrict__ out, int M, int nblk)
{
  __shared__ float sh[256*33];   // per-thread 33-float row; stride 33 -> conflict-free
  int b = blockIdx.x;
  int nb8 = (nblk >> 3) << 3;
  int c = (b < nb8) ? ((b & 7)*(nblk >> 3) + (b >> 3)) : b;
  int t = c*256 + threadIdx.x;
  if (t >= M) return;
  float* row = sh + threadIdx.x*33;
  int m = qidx[t];
  gather_mlp_body(m, qs[3*t+0], qs[3*t+1], qs[3*t+2], row,
                  grid, W1,b1,W2,b2,W3,b3, out, M);
}

// ---------------- fallbacks (ws too small; not used in practice) ----------------
__global__ void __launch_bounds__(256) p2g_atomic_kernel(
    const float* __restrict__ xsr, const float* __restrict__ xsc,
    const float* __restrict__ Wf,  const float* __restrict__ bf,
    float* __restrict__ grid, int N)
{
  int i = blockIdx.x*256 + threadIdx.x;
  if (i >= N) return;
  float sx,sy,sz,dx,dy,dz; int bx,by,bz;
  particle_cell(xsr,i,sx,sy,sz,bx,by,bz,dx,dy,dz);
  float ux = xsc[3*i+0] - sx;
  float uy = xsc[3*i+1] - sy;
  float uz = xsc[3*i+2] - sz;
  float f0 = gelu_f(ux*Wf[0] + uy*Wf[3] + uz*Wf[6] + bf[0]);
  float f1 = gelu_f(ux*Wf[1] + uy*Wf[4] + uz*Wf[7] + bf[1]);
  float f2 = gelu_f(ux*Wf[2] + uy*Wf[5] + uz*Wf[8] + bf[2]);
  float ex = 1.0f - dx, ey = 1.0f - dy, ez = 1.0f - dz;
  auto splat = [&](int xi, int yi, int zi, float w){
    float* p = grid + ((size_t)((((xi<<7)+yi)<<7)+zi) << 3);
    unsafeAtomicAdd(p+0, f0*w);
    unsafeAtomicAdd(p+1, f1*w);
    unsafeAtomicAdd(p+2, f2*w);
    unsafeAtomicAdd(p+3, w);
    unsafeAtomicAdd(p+4, ux*w);
    unsafeAtomicAdd(p+5, uy*w);
    unsafeAtomicAdd(p+6, uz*w);
  };
  splat(bx,  by,  bz,   ex*ey*ez);
  splat(bx,  by,  bz+1, ex*ey*dz);
  splat(bx,  by+1,bz,   ex*dy*ez);
  splat(bx,  by+1,bz+1, ex*dy*dz);
  splat(bx+1,by,  bz,   dx*ey*ez);
  splat(bx+1,by,  bz+1, dx*ey*dz);
  splat(bx+1,by+1,bz,   dx*dy*ez);
  splat(bx+1,by+1,bz+1, dx*dy*dz);
}

__global__ void __launch_bounds__(256) qident_kernel(
    const float* __restrict__ xq, float* __restrict__ qs, int* __restrict__ qidx, int M){
  int i = blockIdx.x*256 + threadIdx.x;
  if (i >= M) return;
  qs[3*i+0] = fminf(fmaxf(xq[3*i+0], 0.0f), 1.0f);
  qs[3*i+1] = fminf(fmaxf(xq[3*i+1], 0.0f), 1.0f);
  qs[3*i+2] = fminf(fmaxf(xq[3*i+2], 0.0f), 1.0f);
  qidx[i] = i;
}

extern "C" void kernel_launch(void* const* d_in, const int* in_sizes, int n_in,
                              void* d_out, int out_size, void* d_ws, size_t ws_size,
                              hipStream_t stream)
{
  const float* xq  = (const float*)d_in[0];
  const float* xsr = (const float*)d_in[1];
  const float* xsc = (const float*)d_in[2];
  const float* Wf  = (const float*)d_in[3];
  const float* bf  = (const float*)d_in[4];
  const float* W1  = (const float*)d_in[5];
  const float* b1  = (const float*)d_in[6];
  const float* W2  = (const float*)d_in[7];
  const float* b2  = (const float*)d_in[8];
  const float* W3  = (const float*)d_in[9];
  const float* b3  = (const float*)d_in[10];
  float* out  = (float*)d_out;
  int M = in_sizes[0]/3;
  int N = in_sizes[1]/3;

  // workspace layout (256B-aligned chunks); cnt and qcnt adjacent -> single memset
  char* W = (char*)d_ws;
  size_t off = 0;
  auto alloc = [&](size_t bytes){ size_t o = off; off = (off + bytes + 255) & ~(size_t)255; return o; };
  size_t o_grid   = alloc((size_t)NCELLS * 8 * sizeof(float));   // 64 MiB
  size_t o_cnt    = alloc((size_t)NCELLS * sizeof(int));         // 8 MiB
  size_t o_qcnt   = alloc((size_t)NQBINS * sizeof(int));         // 128 KB (directly after cnt)
  size_t o_offs   = alloc(((size_t)NCELLS + 1) * sizeof(int));   // 8 MiB
  size_t o_cursor = alloc((size_t)NCELLS * sizeof(int));         // 8 MiB
  size_t o_bsum   = alloc((size_t)(SCAN_BLOCKS + 1) * sizeof(int));
  size_t o_qcur   = alloc((size_t)NQBINS * sizeof(int));         // 128 KB
  size_t o_pf     = alloc((size_t)N * sizeof(float4));           // 8 MB
  size_t o_pu     = alloc((size_t)N * sizeof(float4));           // 8 MB
  size_t o_pz     = alloc((size_t)N * sizeof(float));            // 2 MB
  size_t o_qs     = alloc((size_t)M * 3 * sizeof(float));        // 6 MB
  size_t o_qidx   = alloc((size_t)M * sizeof(int));              // 2 MB
  size_t full_end = off;

  float*  grid   = (float*)(W + o_grid);
  int*    cnt    = (int*)(W + o_cnt);
  int*    qcnt   = (int*)(W + o_qcnt);
  int*    offs   = (int*)(W + o_offs);
  int*    cursor = (int*)(W + o_cursor);
  int*    bsum   = (int*)(W + o_bsum);
  int*    qcur   = (int*)(W + o_qcur);
  float4* pf     = (float4*)(W + o_pf);
  float4* pu     = (float4*)(W + o_pu);
  float*  pz     = (float*)(W + o_pz);
  float*  qs     = (float*)(W + o_qs);
  int*    qidx   = (int*)(W + o_qidx);

  int nthr = (N > M) ? N : M;
  int nblkNM = (nthr + 255) / 256;

  if (full_end <= ws_size) {
    hipMemsetAsync(cnt, 0, (size_t)NCELLS * sizeof(int) + (size_t)NQBINS * sizeof(int), stream);
    hist2_kernel<<<nblkNM, 256, 0, stream>>>(xsr, xq, cnt, qcnt, N, M);
    scan1_kernel<<<SCAN_BLOCKS, 256, 0, stream>>>(cnt, offs, bsum);
    scan2q_kernel<<<1, 1024, 0, stream>>>(bsum, qcnt, qcur);
    scan3_kernel<<<NCELLS/256, 256, 0, stream>>>(offs, bsum, cursor);
    scatter2_kernel<<<nblkNM, 256, 0, stream>>>(xsr, xsc, Wf, bf, xq, cursor, qcur,
                                                pf, pu, pz, qs, qidx, N, M);
    p2g_gather_pair_kernel<<<(NCELLS/2)/256, 256, 0, stream>>>(offs, pf, pu, pz, grid);
  } else {
    hipMemsetAsync(grid, 0, (size_t)NCELLS * 8 * sizeof(float), stream);
    p2g_atomic_kernel<<<(N+255)/256, 256, 0, stream>>>(xsr, xsc, Wf, bf, grid, N);
    qident_kernel<<<(M+255)/256, 256, 0, stream>>>(xq, qs, qidx, M);
  }

  int nblk = (M + 255) / 256;
  gather_mlp_sorted_kernel<<<nblk, 256, 0, stream>>>(qs, qidx, grid, W1,b1,W2,b2,W3,b3, out, M, nblk);
}

// Round 12
// 396.584 us; speedup vs baseline: 1.3916x; 1.0337x over previous
//
#include <hip/hip_runtime.h>
#include <cstdint>

#ifndef JAX_PARTITIONABLE
#define JAX_PARTITIONABLE 1   // modern JAX (>=0.5) default threefry_partitionable
#endif

#define NCELLS (128*128*128)          // 2,097,152
#define SCAN_BLOCKS 1024              // NCELLS / 2048
#define NQBINS (32*32*32)             // coarse query bins (4x4x4 cells each)

typedef _Float16 f16;
typedef f16  half8 __attribute__((ext_vector_type(8)));
typedef float f32x4 __attribute__((ext_vector_type(4)));

#define HSTR 72   // padded row stride (halfs) for [64][64] activation tiles: 144B -> 4-bank row skew
#define WSTR 40   // padded row stride (halfs) for [64][32] W1^T tile

// ---------------- Threefry-2x32, key = (0, 42)  (jax.random.key(42)) ----------------
__device__ __forceinline__ uint32_t rotl32(uint32_t v, int s){ return (v << s) | (v >> (32 - s)); }

__device__ __forceinline__ void tf2x32(uint32_t& x0, uint32_t& x1){
  const uint32_t k0 = 0u, k1 = 42u;
  const uint32_t k2 = 0x1BD11BDAu ^ k0 ^ k1;
  x0 += k0; x1 += k1;
#define TFR(r) { x0 += x1; x1 = rotl32(x1,(r)); x1 ^= x0; }
  TFR(13) TFR(15) TFR(26) TFR(6)
  x0 += k1; x1 += k2 + 1u;
  TFR(17) TFR(29) TFR(16) TFR(24)
  x0 += k2; x1 += k0 + 2u;
  TFR(13) TFR(15) TFR(26) TFR(6)
  x0 += k0; x1 += k1 + 3u;
  TFR(17) TFR(29) TFR(16) TFR(24)
  x0 += k1; x1 += k2 + 4u;
  TFR(13) TFR(15) TFR(26) TFR(6)
  x0 += k2; x1 += k0 + 5u;
#undef TFR
}

// XLA f32 ErfInv (Giles) — exact coefficient match with jax/XLA
__device__ __forceinline__ float erfinv_xla(float x){
  float w = -log1pf(-x*x);
  float p;
  if (w < 5.0f){
    w -= 2.5f;
    p =  2.81022636e-08f;
    p = fmaf(p,w, 3.43273939e-07f);
    p = fmaf(p,w,-3.5233877e-06f);
    p = fmaf(p,w,-4.39150654e-06f);
    p = fmaf(p,w, 0.00021858087f);
    p = fmaf(p,w,-0.00125372503f);
    p = fmaf(p,w,-0.00417768164f);
    p = fmaf(p,w, 0.246640727f);
    p = fmaf(p,w, 1.50140941f);
  } else {
    w = sqrtf(w) - 3.0f;
    p = -0.000200214257f;
    p = fmaf(p,w, 0.000100950558f);
    p = fmaf(p,w, 0.00134934322f);
    p = fmaf(p,w,-0.00367342844f);
    p = fmaf(p,w, 0.00573950773f);
    p = fmaf(p,w,-0.0076224613f);
    p = fmaf(p,w, 0.00943887047f);
    p = fmaf(p,w, 1.00167406f);
    p = fmaf(p,w, 2.83297682f);
  }
  return p*x;
}

// noise[i] = 0.8 * sqrt(2)*erfinv(uniform(-1,1)) with jax bit semantics
__device__ __forceinline__ float noise_at(uint32_t idx, uint32_t half){
#if JAX_PARTITIONABLE
  (void)half;
  uint32_t x0 = 0u, x1 = idx;     // counter = (hi=0, lo=i)
  tf2x32(x0, x1);
  uint32_t bits = x0 ^ x1;        // partitionable 32-bit path: xor-fold of both words
#else
  uint32_t j  = (idx < half) ? idx : (idx - half);
  uint32_t x0 = j, x1 = j + half;
  tf2x32(x0, x1);
  uint32_t bits = (idx < half) ? x0 : x1;
#endif
  float f = __uint_as_float((bits >> 9) | 0x3f800000u) - 1.0f;      // [0,1)
  float u = fmaxf(-0.99999994f, fmaf(f, 2.0f, -0.99999994f));       // (-1,1)
  return (1.41421356f * erfinv_xla(u)) * 0.8f;
}

// jax.nn.gelu approximate=True
__device__ __forceinline__ float tanh_fast(float x){
  float e = __expf(2.0f * x);
  return 1.0f - 2.0f * __builtin_amdgcn_rcpf(e + 1.0f);
}
__device__ __forceinline__ float gelu_f(float x){
  float inner = 0.7978845608028654f * (x + 0.044715f*(x*x*x));
  return 0.5f * x * (1.0f + tanh_fast(inner));
}

// common per-particle geometry
__device__ __forceinline__ void particle_cell(const float* xsr, int i,
                                              float& sx, float& sy, float& sz,
                                              int& bx, int& by, int& bz,
                                              float& dx, float& dy, float& dz){
  sx = fminf(fmaxf(xsr[3*i+0], 0.0f), 1.0f);
  sy = fminf(fmaxf(xsr[3*i+1], 0.0f), 1.0f);
  sz = fminf(fmaxf(xsr[3*i+2], 0.0f), 1.0f);
  float cx = fminf(fmaxf(sx*127.0f, 0.0f), 126.999f);
  float cy = fminf(fmaxf(sy*127.0f, 0.0f), 126.999f);
  float cz = fminf(fmaxf(sz*127.0f, 0.0f), 126.999f);
  float bxf = floorf(cx), byf = floorf(cy), bzf = floorf(cz);
  bx = (int)bxf; by = (int)byf; bz = (int)bzf;
  dx = cx - bxf; dy = cy - byf; dz = cz - bzf;
}

__device__ __forceinline__ int qbin_of(float qx01, float qy01, float qz01){
  int bx = min((int)(qx01*127.0f), 127) >> 2;
  int by = min((int)(qy01*127.0f), 127) >> 2;
  int bz = min((int)(qz01*127.0f), 127) >> 2;
  return (((bx<<5)+by)<<5)+bz;
}

// ---------------- fused histogram: particle cells + query coarse bins ----------------
__global__ void __launch_bounds__(256) hist2_kernel(
    const float* __restrict__ xsr, const float* __restrict__ xq,
    int* __restrict__ cnt, int* __restrict__ qcnt, int N, int M){
  int i = blockIdx.x*256 + threadIdx.x;
  if (i < N){
    float sx,sy,sz,dx,dy,dz; int bx,by,bz;
    particle_cell(xsr,i,sx,sy,sz,bx,by,bz,dx,dy,dz);
    atomicAdd(&cnt[(((bx<<7)+by)<<7)+bz], 1);
  }
  if (i < M){
    float qx01 = fminf(fmaxf(xq[3*i+0], 0.0f), 1.0f);
    float qy01 = fminf(fmaxf(xq[3*i+1], 0.0f), 1.0f);
    float qz01 = fminf(fmaxf(xq[3*i+2], 0.0f), 1.0f);
    atomicAdd(&qcnt[qbin_of(qx01,qy01,qz01)], 1);
  }
}

// exclusive scan stage 1: 1024 blocks x 256 thr x 8 elems
__global__ void __launch_bounds__(256) scan1_kernel(const int* __restrict__ cnt,
                                                    int* __restrict__ offs,
                                                    int* __restrict__ bsum){
  __shared__ int lds[256];
  int t = threadIdx.x;
  int base = blockIdx.x*2048 + t*8;
  const int4* c4 = reinterpret_cast<const int4*>(cnt + base);
  int4 a0 = c4[0], a1 = c4[1];
  int s = a0.x+a0.y+a0.z+a0.w + a1.x+a1.y+a1.z+a1.w;
  lds[t] = s; __syncthreads();
  for (int off = 1; off < 256; off <<= 1){
    int v = (t >= off) ? lds[t-off] : 0;
    __syncthreads();
    lds[t] += v;
    __syncthreads();
  }
  int run = lds[t] - s;
  if (t == 255) bsum[blockIdx.x] = lds[255];
  int* o = offs + base;
  o[0]=run; run+=a0.x; o[1]=run; run+=a0.y; o[2]=run; run+=a0.z; o[3]=run; run+=a0.w;
  o[4]=run; run+=a1.x; o[5]=run; run+=a1.y; o[6]=run; run+=a1.z; o[7]=run;
}

// fused: scan block sums (particles) + full exclusive scan of 32K query-bin counts
__global__ void __launch_bounds__(1024) scan2q_kernel(int* __restrict__ bsum,
                                                      const int* __restrict__ qcnt,
                                                      int* __restrict__ qcur){
  __shared__ int lds[1024];
  int t = threadIdx.x;
  int v = bsum[t];
  lds[t] = v; __syncthreads();
  for (int off = 1; off < 1024; off <<= 1){
    int u = (t >= off) ? lds[t-off] : 0;
    __syncthreads();
    lds[t] += u;
    __syncthreads();
  }
  bsum[t] = lds[t] - v;
  if (t == 1023) bsum[1024] = lds[1023];
  __syncthreads();
  int base = t*32;
  int loc[32];
  int s = 0;
#pragma unroll
  for (int j = 0; j < 32; ++j){ loc[j] = qcnt[base+j]; s += loc[j]; }
  lds[t] = s; __syncthreads();
  for (int off = 1; off < 1024; off <<= 1){
    int u = (t >= off) ? lds[t-off] : 0;
    __syncthreads();
    lds[t] += u;
    __syncthreads();
  }
  int run = lds[t] - s;
#pragma unroll
  for (int j = 0; j < 32; ++j){ qcur[base+j] = run; run += loc[j]; }
}

// stage 3: add block offsets, init cursor, write sentinel
__global__ void __launch_bounds__(256) scan3_kernel(int* __restrict__ offs,
                                                    const int* __restrict__ bsum,
                                                    int* __restrict__ cursor){
  int i = blockIdx.x*256 + threadIdx.x;
  int o = offs[i] + bsum[i >> 11];
  offs[i] = o; cursor[i] = o;
  if (i == 0) offs[NCELLS] = bsum[SCAN_BLOCKS];
}

// fused scatter: particle payload bump-alloc + query coarse-sorted stash
__global__ void __launch_bounds__(256) scatter2_kernel(
    const float* __restrict__ xsr, const float* __restrict__ xsc,
    const float* __restrict__ Wf,  const float* __restrict__ bf,
    const float* __restrict__ xq,
    int* __restrict__ cursor, int* __restrict__ qcur,
    float4* __restrict__ pf, float4* __restrict__ pu, float* __restrict__ pz,
    float* __restrict__ qs, int* __restrict__ qidx, int N, int M){
  int i = blockIdx.x*256 + threadIdx.x;
  if (i < N){
    float sx,sy,sz,dx,dy,dz; int bx,by,bz;
    particle_cell(xsr,i,sx,sy,sz,bx,by,bz,dx,dy,dz);
    float ux = xsc[3*i+0] - sx;
    float uy = xsc[3*i+1] - sy;
    float uz = xsc[3*i+2] - sz;
    float f0 = gelu_f(ux*Wf[0] + uy*Wf[3] + uz*Wf[6] + bf[0]);
    float f1 = gelu_f(ux*Wf[1] + uy*Wf[4] + uz*Wf[7] + bf[1]);
    float f2 = gelu_f(ux*Wf[2] + uy*Wf[5] + uz*Wf[8] + bf[2]);
    int bin = (((bx<<7)+by)<<7)+bz;
    int pos = atomicAdd(&cursor[bin], 1);
    pf[pos] = make_float4(f0, f1, f2, dx);
    pu[pos] = make_float4(ux, uy, uz, dy);
    pz[pos] = dz;
  }
  if (i < M){
    float qx01 = fminf(fmaxf(xq[3*i+0], 0.0f), 1.0f);
    float qy01 = fminf(fmaxf(xq[3*i+1], 0.0f), 1.0f);
    float qz01 = fminf(fmaxf(xq[3*i+2], 0.0f), 1.0f);
    int pos = atomicAdd(&qcur[qbin_of(qx01,qy01,qz01)], 1);
    qs[3*pos+0] = qx01; qs[3*pos+1] = qy01; qs[3*pos+2] = qz01;
    qidx[pos] = i;
  }
}

// z-pair per-cell gather (single contiguous range, branchless zone weights)
__global__ void __launch_bounds__(256) p2g_gather_pair_kernel(
    const int* __restrict__ offs,
    const float4* __restrict__ pf, const float4* __restrict__ pu,
    const float* __restrict__ pz, float* __restrict__ grid){
  int tid = blockIdx.x*256 + threadIdx.x;   // exactly NCELLS/2 threads
  int zg = tid & 63, y = (tid >> 6) & 127, x = tid >> 13;
  int z0 = zg << 1;
  float a0[2]={0,0},a1[2]={0,0},a2[2]={0,0},a3[2]={0,0},a4[2]={0,0},a5[2]={0,0},a6[2]={0,0};
#pragma unroll
  for (int ox = 0; ox < 2; ++ox){
    int bx = x - ox; if (bx < 0) continue;
#pragma unroll
    for (int oy = 0; oy < 2; ++oy){
      int by = y - oy; if (by < 0) continue;
      int b0 = ((((bx<<7)+by)<<7)) + z0;
      int em = offs[b0];
      int sm = (z0 > 0) ? offs[b0-1] : em;
      int e0 = offs[b0+1];
      int e1 = offs[b0+2];
      for (int p = sm; p < e1; ++p){
        float4 A = pf[p]; float4 B = pu[p]; float dz = pz[p];
        float wx = ox ? A.w : 1.0f - A.w;
        float wy = oy ? B.w : 1.0f - B.w;
        float wxy = wx*wy;
        float omdz = 1.0f - dz;
        float w0 = (p < em) ? dz : ((p < e0) ? omdz : 0.0f);
        float w1 = (p < em) ? 0.0f : ((p < e0) ? dz : omdz);
        w0 *= wxy; w1 *= wxy;
        a0[0]=fmaf(A.x,w0,a0[0]); a1[0]=fmaf(A.y,w0,a1[0]); a2[0]=fmaf(A.z,w0,a2[0]);
        a3[0]+=w0; a4[0]=fmaf(B.x,w0,a4[0]); a5[0]=fmaf(B.y,w0,a5[0]); a6[0]=fmaf(B.z,w0,a6[0]);
        a0[1]=fmaf(A.x,w1,a0[1]); a1[1]=fmaf(A.y,w1,a1[1]); a2[1]=fmaf(A.z,w1,a2[1]);
        a3[1]+=w1; a4[1]=fmaf(B.x,w1,a4[1]); a5[1]=fmaf(B.y,w1,a5[1]); a6[1]=fmaf(B.z,w1,a6[1]);
      }
    }
  }
  int cell0 = ((((x<<7)+y)<<7)) + z0;
  float4* g = reinterpret_cast<float4*>(grid + ((size_t)cell0 << 3));
  g[0] = make_float4(a0[0],a1[0],a2[0],a3[0]);
  g[1] = make_float4(a4[0],a5[0],a6[0],0.0f);
  g[2] = make_float4(a0[1],a1[1],a2[1],a3[1]);
  g[3] = make_float4(a4[1],a5[1],a6[1],0.0f);
}

// ---------------- fused gather + MFMA MLP ----------------
// Per wave: 64 queries. MLP via v_mfma_f32_16x16x32_f16 (A[m=lane&15][k=(lane>>4)*8+j],
// C/D col=lane&15,row=(lane>>4)*4+reg). Activations round-trip a per-wave LDS tile.
__global__ void __launch_bounds__(256, 3) gather_mlp_sorted_kernel(
    const float* __restrict__ qs,  const int* __restrict__ qidx,
    const float* __restrict__ grid,
    const float* __restrict__ W1,  const float* __restrict__ b1,
    const float* __restrict__ W2,  const float* __restrict__ b2,
    const float* __restrict__ W3,  const float* __restrict__ b3,
    float* __restrict__ out, int M, int nblk)
{
  __shared__ f16  w1t[64*WSTR];     // W1^T [n][k], k padded 24->32, stride 40
  __shared__ f16  w2t[64*HSTR];     // W2^T [n][k], stride 72
  __shared__ float b1s[64], b2s[64];
  __shared__ f16  hbuf[4][64*HSTR]; // per-wave activation tile [row][col/k], stride 72

  // stage weights (block-cooperative)
  for (int i = threadIdx.x; i < 64*32; i += 256){
    int n = i >> 5, k = i & 31;
    w1t[n*WSTR + k] = (k < 24) ? (f16)W1[k*64 + n] : (f16)0.0f;
  }
  for (int i = threadIdx.x; i < 64*64; i += 256){
    int n = i >> 6, k = i & 63;
    w2t[n*HSTR + k] = (f16)W2[k*64 + n];
  }
  if (threadIdx.x < 64){ b1s[threadIdx.x] = b1[threadIdx.x]; b2s[threadIdx.x] = b2[threadIdx.x]; }
  __syncthreads();

  int b = blockIdx.x;
  int nb8 = (nblk >> 3) << 3;
  int c = (b < nb8) ? ((b & 7)*(nblk >> 3) + (b >> 3)) : b;   // XCD-contiguous chunks
  int t = c*256 + threadIdx.x;
  bool active = (t < M);
  int tc = active ? t : (M - 1);
  int m = qidx[tc];

  float qx01 = qs[3*tc+0], qy01 = qs[3*tc+1], qz01 = qs[3*tc+2];
  float qx = qx01*127.0f, qy = qy01*127.0f, qz = qz01*127.0f;

  // ---- gather: 8 MC paths, trilerp ----
  float r0=0.f,r1=0.f,r2=0.f,r3=0.f,r4=0.f,r5=0.f,r6=0.f;
  const uint32_t KSTRIDE = 3u*(uint32_t)M;
  const uint32_t HALF    = 4u*KSTRIDE;
  uint32_t m3 = 3u*(uint32_t)m;

  for (int k = 0; k < 8; ++k) {
    uint32_t base = (uint32_t)k*KSTRIDE + m3;
    float px = qx + noise_at(base+0u, HALF);
    float py = qy + noise_at(base+1u, HALF);
    float pz = qz + noise_at(base+2u, HALF);
    float fxf = floorf(px), fyf = floorf(py), fzf = floorf(pz);
    float fx = px - fxf, fy = py - fyf, fz = pz - fzf;
    int lx = (int)fxf, ly = (int)fyf, lz = (int)fzf;
    int x0i = min(max(lx,0),127),   x1i = min(max(lx+1,0),127);
    int y0i = min(max(ly,0),127),   y1i = min(max(ly+1,0),127);
    int z0i = min(max(lz,0),127),   z1i = min(max(lz+1,0),127);
    float ex = 1.0f-fx, ey = 1.0f-fy, ez = 1.0f-fz;

    auto corner = [&](int xi,int yi,int zi,float w){
      const float4* p = reinterpret_cast<const float4*>(grid + ((size_t)((((xi<<7)+yi)<<7)+zi) << 3));
      float4 g0 = p[0]; float4 g1 = p[1];
      r0 = fmaf(g0.x, w, r0); r1 = fmaf(g0.y, w, r1); r2 = fmaf(g0.z, w, r2);
      r3 = fmaf(g0.w, w, r3); r4 = fmaf(g1.x, w, r4); r5 = fmaf(g1.y, w, r5);
      r6 = fmaf(g1.z, w, r6);
    };
    corner(x0i,y0i,z0i, ex*ey*ez);
    corner(x0i,y0i,z1i, ex*ey*fz);
    corner(x0i,y1i,z0i, ex*fy*ez);
    corner(x0i,y1i,z1i, ex*fy*fz);
    corner(x1i,y0i,z0i, fx*ey*ez);
    corner(x1i,y0i,z1i, fx*ey*fz);
    corner(x1i,y1i,z0i, fx*fy*ez);
    corner(x1i,y1i,z1i, fx*fy*fz);
  }

  float dmean = r3*0.125f;
  float denom = fmaxf(dmean, 1e-5f);
  float maskf = (dmean > 1e-5f) ? 1.0f : 0.0f;
  float s = 0.125f/denom*maskf;
  float fn0 = r0*s, fn1 = r1*s, fn2 = r2*s;
  float un0 = r4*s, un1 = r5*s, un2 = r6*s;

  float dec[24];
  dec[0]=fn0; dec[1]=fn1; dec[2]=fn2; dec[3]=un0; dec[4]=un1; dec[5]=un2;
  dec[6]  = __builtin_amdgcn_sinf(0.5f*qx01);   // v_sin input is revolutions
  dec[7]  = __builtin_amdgcn_sinf(0.5f*qy01);
  dec[8]  = __builtin_amdgcn_sinf(0.5f*qz01);
  dec[9]  = __builtin_amdgcn_cosf(0.5f*qx01);
  dec[10] = __builtin_amdgcn_cosf(0.5f*qy01);
  dec[11] = __builtin_amdgcn_cosf(0.5f*qz01);
  dec[12] = __builtin_amdgcn_sinf(qx01);
  dec[13] = __builtin_amdgcn_sinf(qy01);
  dec[14] = __builtin_amdgcn_sinf(qz01);
  dec[15] = __builtin_amdgcn_cosf(qx01);
  dec[16] = __builtin_amdgcn_cosf(qy01);
  dec[17] = __builtin_amdgcn_cosf(qz01);
  dec[18] = __builtin_amdgcn_sinf(2.0f*qx01);
  dec[19] = __builtin_amdgcn_sinf(2.0f*qy01);
  dec[20] = __builtin_amdgcn_sinf(2.0f*qz01);
  dec[21] = __builtin_amdgcn_cosf(2.0f*qx01);
  dec[22] = __builtin_amdgcn_cosf(2.0f*qy01);
  dec[23] = __builtin_amdgcn_cosf(2.0f*qz01);

  // ---- MLP via MFMA ----
  int lane = threadIdx.x & 63;
  int wv   = threadIdx.x >> 6;
  f16* hb = &hbuf[wv][0];
  int colg = lane & 15;         // in-tile col (C layout) / A row
  int kq   = lane >> 4;         // quad id: A k-chunk = kq*8; C row base = kq*4

  // stage dec (fp16, k padded to 32) into hb[row=lane][k]
#pragma unroll
  for (int j = 0; j < 24; ++j) hb[lane*HSTR + j] = (f16)dec[j];
#pragma unroll
  for (int j = 24; j < 32; ++j) hb[lane*HSTR + j] = (f16)0.0f;

  // layer 1: H[64x64] = DEC[64x32] @ W1[32x64]; A-frags loaded upfront, then overwrite hb with gelu(H)
  half8 a1[4];
#pragma unroll
  for (int mt = 0; mt < 4; ++mt)
    a1[mt] = *reinterpret_cast<const half8*>(&hb[(mt*16 + colg)*HSTR + kq*8]);

#pragma unroll
  for (int nt = 0; nt < 4; ++nt){
    half8 bf1 = *reinterpret_cast<const half8*>(&w1t[(nt*16 + colg)*WSTR + kq*8]);
    float bias = b1s[nt*16 + colg];
#pragma unroll
    for (int mt = 0; mt < 4; ++mt){
      f32x4 z = {0.f,0.f,0.f,0.f};
      z = __builtin_amdgcn_mfma_f32_16x16x32_f16(a1[mt], bf1, z, 0, 0, 0);
#pragma unroll
      for (int reg = 0; reg < 4; ++reg){
        float hv = gelu_f(z[reg] + bias);
        hb[(mt*16 + kq*4 + reg)*HSTR + nt*16 + colg] = (f16)hv;
      }
    }
  }

  // layer 2: G[64x64] = gelu(H)[64x64] @ W2[64x64]; A-frags (2 k-chunks) upfront, overwrite hb with gelu(G)
  half8 a2[4][2];
#pragma unroll
  for (int mt = 0; mt < 4; ++mt)
#pragma unroll
    for (int kc = 0; kc < 2; ++kc)
      a2[mt][kc] = *reinterpret_cast<const half8*>(&hb[(mt*16 + colg)*HSTR + kc*32 + kq*8]);

#pragma unroll
  for (int nt = 0; nt < 4; ++nt){
    half8 bf20 = *reinterpret_cast<const half8*>(&w2t[(nt*16 + colg)*HSTR + kq*8]);
    half8 bf21 = *reinterpret_cast<const half8*>(&w2t[(nt*16 + colg)*HSTR + 32 + kq*8]);
    float bias = b2s[nt*16 + colg];
#pragma unroll
    for (int mt = 0; mt < 4; ++mt){
      f32x4 z = {0.f,0.f,0.f,0.f};
      z = __builtin_amdgcn_mfma_f32_16x16x32_f16(a2[mt][0], bf20, z, 0, 0, 0);
      z = __builtin_amdgcn_mfma_f32_16x16x32_f16(a2[mt][1], bf21, z, 0, 0, 0);
#pragma unroll
      for (int reg = 0; reg < 4; ++reg){
        float gv = gelu_f(z[reg] + bias);
        hb[(mt*16 + kq*4 + reg)*HSTR + nt*16 + colg] = (f16)gv;
      }
    }
  }

  // layer 3: per-lane 64->3 from own row of gelu(G)
  float o0 = b3[0], o1 = b3[1], o2 = b3[2];
#pragma unroll
  for (int c8 = 0; c8 < 8; ++c8){
    half8 hv = *reinterpret_cast<const half8*>(&hb[lane*HSTR + c8*8]);
#pragma unroll
    for (int j = 0; j < 8; ++j){
      float g = (float)hv[j];
      int col = c8*8 + j;
      o0 = fmaf(g, W3[3*col+0], o0);
      o1 = fmaf(g, W3[3*col+1], o1);
      o2 = fmaf(g, W3[3*col+2], o2);
    }
  }

  if (active){
    out[3*m+0] = fminf(fmaxf(un0 + o0, 0.001f), 0.999f);
    out[3*m+1] = fminf(fmaxf(un1 + o1, 0.001f), 0.999f);
    out[3*m+2] = fminf(fmaxf(un2 + o2, 0.001f), 0.999f);
  }
}

// ---------------- fallbacks (ws too small; not used in practice) ----------------
__global__ void __launch_bounds__(256) p2g_atomic_kernel(
    const float* __restrict__ xsr, const float* __restrict__ xsc,
    const float* __restrict__ Wf,  const float* __restrict__ bf,
    float* __restrict__ grid, int N)
{
  int i = blockIdx.x*256 + threadIdx.x;
  if (i >= N) return;
  float sx,sy,sz,dx,dy,dz; int bx,by,bz;
  particle_cell(xsr,i,sx,sy,sz,bx,by,bz,dx,dy,dz);
  float ux = xsc[3*i+0] - sx;
  float uy = xsc[3*i+1] - sy;
  float uz = xsc[3*i+2] - sz;
  float f0 = gelu_f(ux*Wf[0] + uy*Wf[3] + uz*Wf[6] + bf[0]);
  float f1 = gelu_f(ux*Wf[1] + uy*Wf[4] + uz*Wf[7] + bf[1]);
  float f2 = gelu_f(ux*Wf[2] + uy*Wf[5] + uz*Wf[8] + bf[2]);
  float ex = 1.0f - dx, ey = 1.0f - dy, ez = 1.0f - dz;
  auto splat = [&](int xi, int yi, int zi, float w){
    float* p = grid + ((size_t)((((xi<<7)+yi)<<7)+zi) << 3);
    unsafeAtomicAdd(p+0, f0*w);
    unsafeAtomicAdd(p+1, f1*w);
    unsafeAtomicAdd(p+2, f2*w);
    unsafeAtomicAdd(p+3, w);
    unsafeAtomicAdd(p+4, ux*w);
    unsafeAtomicAdd(p+5, uy*w);
    unsafeAtomicAdd(p+6, uz*w);
  };
  splat(bx,  by,  bz,   ex*ey*ez);
  splat(bx,  by,  bz+1, ex*ey*dz);
  splat(bx,  by+1,bz,   ex*dy*ez);
  splat(bx,  by+1,bz+1, ex*dy*dz);
  splat(bx+1,by,  bz,   dx*ey*ez);
  splat(bx+1,by,  bz+1, dx*ey*dz);
  splat(bx+1,by+1,bz,   dx*dy*ez);
  splat(bx+1,by+1,bz+1, dx*dy*dz);
}

__global__ void __launch_bounds__(256) qident_kernel(
    const float* __restrict__ xq, float* __restrict__ qs, int* __restrict__ qidx, int M){
  int i = blockIdx.x*256 + threadIdx.x;
  if (i >= M) return;
  qs[3*i+0] = fminf(fmaxf(xq[3*i+0], 0.0f), 1.0f);
  qs[3*i+1] = fminf(fmaxf(xq[3*i+1], 0.0f), 1.0f);
  qs[3*i+2] = fminf(fmaxf(xq[3*i+2], 0.0f), 1.0f);
  qidx[i] = i;
}

extern "C" void kernel_launch(void* const* d_in, const int* in_sizes, int n_in,
                              void* d_out, int out_size, void* d_ws, size_t ws_size,
                              hipStream_t stream)
{
  const float* xq  = (const float*)d_in[0];
  const float* xsr = (const float*)d_in[1];
  const float* xsc = (const float*)d_in[2];
  const float* Wf  = (const float*)d_in[3];
  const float* bf  = (const float*)d_in[4];
  const float* W1  = (const float*)d_in[5];
  const float* b1  = (const float*)d_in[6];
  const float* W2  = (const float*)d_in[7];
  const float* b2  = (const float*)d_in[8];
  const float* W3  = (const float*)d_in[9];
  const float* b3  = (const float*)d_in[10];
  float* out  = (float*)d_out;
  int M = in_sizes[0]/3;
  int N = in_sizes[1]/3;

  // workspace layout (256B-aligned chunks); cnt and qcnt adjacent -> single memset
  char* W = (char*)d_ws;
  size_t off = 0;
  auto alloc = [&](size_t bytes){ size_t o = off; off = (off + bytes + 255) & ~(size_t)255; return o; };
  size_t o_grid   = alloc((size_t)NCELLS * 8 * sizeof(float));   // 64 MiB
  size_t o_cnt    = alloc((size_t)NCELLS * sizeof(int));         // 8 MiB
  size_t o_qcnt   = alloc((size_t)NQBINS * sizeof(int));         // 128 KB (directly after cnt)
  size_t o_offs   = alloc(((size_t)NCELLS + 1) * sizeof(int));   // 8 MiB
  size_t o_cursor = alloc((size_t)NCELLS * sizeof(int));         // 8 MiB
  size_t o_bsum   = alloc((size_t)(SCAN_BLOCKS + 1) * sizeof(int));
  size_t o_qcur   = alloc((size_t)NQBINS * sizeof(int));         // 128 KB
  size_t o_pf     = alloc((size_t)N * sizeof(float4));           // 8 MB
  size_t o_pu     = alloc((size_t)N * sizeof(float4));           // 8 MB
  size_t o_pz     = alloc((size_t)N * sizeof(float));            // 2 MB
  size_t o_qs     = alloc((size_t)M * 3 * sizeof(float));        // 6 MB
  size_t o_qidx   = alloc((size_t)M * sizeof(int));              // 2 MB
  size_t full_end = off;

  float*  grid   = (float*)(W + o_grid);
  int*    cnt    = (int*)(W + o_cnt);
  int*    qcnt   = (int*)(W + o_qcnt);
  int*    offs   = (int*)(W + o_offs);
  int*    cursor = (int*)(W + o_cursor);
  int*    bsum   = (int*)(W + o_bsum);
  int*    qcur   = (int*)(W + o_qcur);
  float4* pf     = (float4*)(W + o_pf);
  float4* pu     = (float4*)(W + o_pu);
  float*  pz     = (float*)(W + o_pz);
  float*  qs     = (float*)(W + o_qs);
  int*    qidx   = (int*)(W + o_qidx);

  int nthr = (N > M) ? N : M;
  int nblkNM = (nthr + 255) / 256;

  if (full_end <= ws_size) {
    hipMemsetAsync(cnt, 0, (size_t)NCELLS * sizeof(int) + (size_t)NQBINS * sizeof(int), stream);
    hist2_kernel<<<nblkNM, 256, 0, stream>>>(xsr, xq, cnt, qcnt, N, M);
    scan1_kernel<<<SCAN_BLOCKS, 256, 0, stream>>>(cnt, offs, bsum);
    scan2q_kernel<<<1, 1024, 0, stream>>>(bsum, qcnt, qcur);
    scan3_kernel<<<NCELLS/256, 256, 0, stream>>>(offs, bsum, cursor);
    scatter2_kernel<<<nblkNM, 256, 0, stream>>>(xsr, xsc, Wf, bf, xq, cursor, qcur,
                                                pf, pu, pz, qs, qidx, N, M);
    p2g_gather_pair_kernel<<<(NCELLS/2)/256, 256, 0, stream>>>(offs, pf, pu, pz, grid);
  } else {
    hipMemsetAsync(grid, 0, (size_t)NCELLS * 8 * sizeof(float), stream);
    p2g_atomic_kernel<<<(N+255)/256, 256, 0, stream>>>(xsr, xsc, Wf, bf, grid, N);
    qident_kernel<<<(M+255)/256, 256, 0, stream>>>(xq, qs, qidx, M);
  }

  int nblk = (M + 255) / 256;
  gather_mlp_sorted_kernel<<<nblk, 256, 0, stream>>>(qs, qidx, grid, W1,b1,W2,b2,W3,b3, out, M, nblk);
}